// Round 5
// baseline (919.309 us; speedup 1.0000x reference)
//
#include <hip/hip_runtime.h>

#define RFL(x) __builtin_amdgcn_readfirstlane((int)(x))

// Activations in batch-last layout [feature, B]; lanes = batch (coalesced).

// ---------------- transpose x[B,784] -> xT[784, Bc] ----------------
__global__ __launch_bounds__(256) void k_tr(const float* __restrict__ x,
                                            float* __restrict__ xT, int Bc) {
  __shared__ float t[32][33];
  const int b0 = blockIdx.x * 32;
  const int f0 = blockIdx.y * 32;
  const int tx = threadIdx.x, ty = threadIdx.y;
  for (int r = ty; r < 32; r += 8) {
    const int f = f0 + tx;
    t[r][tx] = (f < 784) ? x[(size_t)(b0 + r) * 784 + f] : 0.f;
  }
  __syncthreads();
  for (int r = ty; r < 32; r += 8) {
    const int f = f0 + r;
    if (f < 784) xT[(size_t)f * Bc + b0 + tx] = t[tx][r];
  }
}

// ---------------- LC1: [1,28,28] -> [16,13,13], stride 2, relu -------------
__global__ __launch_bounds__(256) void k_lc1(const float* __restrict__ in,
                                             const float* __restrict__ w,
                                             const float* __restrict__ bias,
                                             float* __restrict__ out, int B) {
  const int b = blockIdx.x * 64 + threadIdx.x;
  const int ho = blockIdx.y;
  const int o0 = threadIdx.y * 4;  // no RFL: avoid forced scalar-load chains
  float xv[3][27];
#pragma unroll
  for (int r = 0; r < 3; ++r)
#pragma unroll
    for (int col = 0; col < 27; ++col)
      xv[r][col] = in[(size_t)((2 * ho + r) * 28 + col) * B + b];
  float acc[4][13];
#pragma unroll
  for (int oo = 0; oo < 4; ++oo)
#pragma unroll
    for (int wo = 0; wo < 13; ++wo)
      acc[oo][wo] = bias[(o0 + oo) * 169 + ho * 13 + wo];
#pragma unroll
  for (int oo = 0; oo < 4; ++oo)
#pragma unroll
    for (int wo = 0; wo < 13; ++wo) {
      const float* wp = w + (size_t)((o0 + oo) * 169 + ho * 13 + wo) * 9;
#pragma unroll
      for (int kh = 0; kh < 3; ++kh)
#pragma unroll
        for (int kw = 0; kw < 3; ++kw)
          acc[oo][wo] = fmaf(xv[kh][2 * wo + kw], wp[kh * 3 + kw], acc[oo][wo]);
    }
#pragma unroll
  for (int oo = 0; oo < 4; ++oo)
#pragma unroll
    for (int wo = 0; wo < 13; ++wo)
      out[(size_t)((o0 + oo) * 169 + ho * 13 + wo) * B + b] =
          fmaxf(acc[oo][wo], 0.f);
}

// ---------------- LC2: [16,13,13] -> [32,6,6], stride 2, relu --------------
// grid (B/64, 8 = oblk*2+hh), block (64,4). Lane = 1 batch. Per c: stage
// 7x13x64 (23.3 KB) pipelined one c ahead; rolling 3-row register window.
#define LC2_ROW(dst, r)                                      \
  _Pragma("unroll") for (int col = 0; col < 13; ++col)       \
      dst[col] = Xs[((r) * 13 + col) * 64 + lane];

#define LC2_COMP(hl, R0, R1, R2)                                          \
  _Pragma("unroll") for (int oo = 0; oo < 2; ++oo) {                      \
    const float* wp = w + (((size_t)(obase + oo) * 16 + c) * 36 +         \
                           hh * 18 + (hl) * 6) * 9;                       \
    _Pragma("unroll") for (int wo = 0; wo < 6; ++wo) {                    \
      float a = acc[oo][(hl) * 6 + wo];                                   \
      _Pragma("unroll") for (int kw = 0; kw < 3; ++kw) {                  \
        a = fmaf(R0[2 * wo + kw], wp[wo * 9 + kw], a);                    \
        a = fmaf(R1[2 * wo + kw], wp[wo * 9 + 3 + kw], a);                \
        a = fmaf(R2[2 * wo + kw], wp[wo * 9 + 6 + kw], a);                \
      }                                                                   \
      acc[oo][(hl) * 6 + wo] = a;                                         \
    }                                                                     \
  }

__global__ __launch_bounds__(256, 3) void k_lc2(const float* __restrict__ in,
                                                const float* __restrict__ w,
                                                const float* __restrict__ bias,
                                                float* __restrict__ out,
                                                int B) {
  __shared__ float Xs[7 * 13 * 64];
  const int lane = threadIdx.x;
  const int wv = threadIdx.y;
  const int tid = wv * 64 + lane;
  const int b0 = blockIdx.x * 64;
  const int oblk = blockIdx.y >> 1, hh = blockIdx.y & 1;
  const int obase = oblk * 8 + wv * 2;
  const int row0 = hh * 6;
  const size_t cstep = (size_t)169 * B;

  float acc[2][18];
#pragma unroll
  for (int oo = 0; oo < 2; ++oo)
#pragma unroll
    for (int p = 0; p < 18; ++p)
      acc[oo][p] = bias[(obase + oo) * 36 + hh * 18 + p];

  // staging map: f4 in [0,1456): row=f4/208, col=(f4%208)>>4, bq=f4&15
  unsigned off[6];
  bool ok[6];
#pragma unroll
  for (int i = 0; i < 6; ++i) {
    const int f4 = tid + i * 256;
    ok[i] = f4 < 1456;
    const int row = f4 / 208;
    const int rem = f4 - row * 208;
    const int col = rem >> 4, bq = rem & 15;
    off[i] = (unsigned)(((row0 + row) * 13 + col) * B + b0 + bq * 4);
  }

  float4 v[6];
#pragma unroll
  for (int i = 0; i < 6; ++i)
    if (ok[i]) v[i] = *(const float4*)&in[off[i]];

#pragma unroll 1
  for (int c = 0; c < 16; ++c) {
    __syncthreads();  // all waves done reading Xs from previous c
#pragma unroll
    for (int i = 0; i < 6; ++i)
      if (ok[i]) *(float4*)&Xs[(tid + i * 256) * 4] = v[i];
    __syncthreads();
    if (c < 15) {
      const float* nin = in + (size_t)(c + 1) * cstep;
#pragma unroll
      for (int i = 0; i < 6; ++i)
        if (ok[i]) v[i] = *(const float4*)&nin[off[i]];
    }
    float xr0[13], xr1[13], xr2[13];
    LC2_ROW(xr0, 0) LC2_ROW(xr1, 1) LC2_ROW(xr2, 2)
    LC2_COMP(0, xr0, xr1, xr2)
    LC2_ROW(xr0, 3) LC2_ROW(xr1, 4)
    LC2_COMP(1, xr2, xr0, xr1)
    LC2_ROW(xr2, 5) LC2_ROW(xr0, 6)
    LC2_COMP(2, xr1, xr2, xr0)
  }
#pragma unroll
  for (int oo = 0; oo < 2; ++oo)
#pragma unroll
    for (int p = 0; p < 18; ++p)
      out[(size_t)((obase + oo) * 36 + hh * 18 + p) * B + b0 + lane] =
          fmaxf(acc[oo][p], 0.f);
}

// ---------------- LC3: [32,6,6] -> [64,4,4], stride 1, no relu -------------
// grid (B/64, 8 oblk), block (64,4). Lane = 1 batch. Stage 6x6x64 (9.2 KB)
// pipelined one c ahead; whole plane in registers (xv[36]).
__global__ __launch_bounds__(256, 4) void k_lc3(const float* __restrict__ in,
                                                const float* __restrict__ w,
                                                const float* __restrict__ bias,
                                                float* __restrict__ out,
                                                int B) {
  __shared__ float Xs[36 * 64];
  const int lane = threadIdx.x;
  const int wv = threadIdx.y;
  const int tid = wv * 64 + lane;
  const int b0 = blockIdx.x * 64;
  const int obase = blockIdx.y * 8 + wv * 2;
  const size_t cstep = (size_t)36 * B;

  float acc[2][16];
#pragma unroll
  for (int oo = 0; oo < 2; ++oo)
#pragma unroll
    for (int p = 0; p < 16; ++p) acc[oo][p] = bias[(obase + oo) * 16 + p];

  unsigned off[3];
  bool ok[3];
#pragma unroll
  for (int i = 0; i < 3; ++i) {
    const int f4 = tid + i * 256;
    ok[i] = f4 < 576;
    const int pos = f4 >> 4, bq = f4 & 15;
    off[i] = (unsigned)(pos * B + b0 + bq * 4);
  }

  float4 v[3];
#pragma unroll
  for (int i = 0; i < 3; ++i)
    if (ok[i]) v[i] = *(const float4*)&in[off[i]];

#pragma unroll 1
  for (int c = 0; c < 32; ++c) {
    __syncthreads();
#pragma unroll
    for (int i = 0; i < 3; ++i)
      if (ok[i]) *(float4*)&Xs[(tid + i * 256) * 4] = v[i];
    __syncthreads();
    if (c < 31) {
      const float* nin = in + (size_t)(c + 1) * cstep;
#pragma unroll
      for (int i = 0; i < 3; ++i)
        if (ok[i]) v[i] = *(const float4*)&nin[off[i]];
    }
    float xv[36];
#pragma unroll
    for (int p = 0; p < 36; ++p) xv[p] = Xs[p * 64 + lane];
#pragma unroll
    for (int oo = 0; oo < 2; ++oo) {
      const float* wp = w + ((size_t)(obase + oo) * 32 + c) * 16 * 9;
#pragma unroll
      for (int ho = 0; ho < 4; ++ho)
#pragma unroll
        for (int wo = 0; wo < 4; ++wo) {
          float a = acc[oo][ho * 4 + wo];
#pragma unroll
          for (int kh = 0; kh < 3; ++kh)
#pragma unroll
            for (int kw = 0; kw < 3; ++kw)
              a = fmaf(xv[(ho + kh) * 6 + wo + kw],
                       wp[(ho * 4 + wo) * 9 + kh * 3 + kw], a);
          acc[oo][ho * 4 + wo] = a;
        }
    }
  }
#pragma unroll
  for (int oo = 0; oo < 2; ++oo)
#pragma unroll
    for (int p = 0; p < 16; ++p)
      out[(size_t)((obase + oo) * 16 + p) * B + b0 + lane] = acc[oo][p];
}

// ---------------- FC1: SGEMM h4[512,B] = relu(fw1[512,1024] @ h3[1024,B]) --
__global__ __launch_bounds__(256) void k_fc1(const float* __restrict__ in,
                                             const float* __restrict__ fw1,
                                             const float* __restrict__ fb1,
                                             float* __restrict__ out, int B) {
  __shared__ float Wt[2][16][128];
  __shared__ float At[2][16][128];
  const int tid = threadIdx.x;
  const int tx = tid & 15, ty = tid >> 4;
  const int b0 = blockIdx.x * 128, j0 = blockIdx.y * 128;
  const int wj = tid >> 1, wk0 = (tid & 1) * 8;
  const int ak = tid >> 4, ab = (tid & 15) * 8;
  const float* wsrc = fw1 + (size_t)(j0 + wj) * 1024 + wk0;
  const float* asrc = in + (size_t)ak * B + b0 + ab;

  float4 wr0 = *(const float4*)(wsrc);
  float4 wr1 = *(const float4*)(wsrc + 4);
  float4 ar0 = *(const float4*)(asrc);
  float4 ar1 = *(const float4*)(asrc + 4);

  float acc[8][8];
#pragma unroll
  for (int jr = 0; jr < 8; ++jr)
#pragma unroll
    for (int bc = 0; bc < 8; ++bc) acc[jr][bc] = 0.f;

#pragma unroll
  for (int i = 0; i < 4; ++i) Wt[0][wk0 + i][wj] = ((const float*)&wr0)[i];
#pragma unroll
  for (int i = 0; i < 4; ++i) Wt[0][wk0 + 4 + i][wj] = ((const float*)&wr1)[i];
  *(float4*)&At[0][ak][ab] = ar0;
  *(float4*)&At[0][ak][ab + 4] = ar1;
  __syncthreads();

  for (int t = 0; t < 64; ++t) {
    const int cur = t & 1;
    if (t < 63) {
      const float* wp = wsrc + (t + 1) * 16;
      wr0 = *(const float4*)(wp);
      wr1 = *(const float4*)(wp + 4);
      const float* ap = asrc + (size_t)(t + 1) * 16 * B;
      ar0 = *(const float4*)(ap);
      ar1 = *(const float4*)(ap + 4);
    }
#pragma unroll
    for (int k = 0; k < 16; ++k) {
      float4 wl = *(const float4*)&Wt[cur][k][ty * 4];
      float4 wh = *(const float4*)&Wt[cur][k][64 + ty * 4];
      float4 al = *(const float4*)&At[cur][k][tx * 4];
      float4 ah = *(const float4*)&At[cur][k][64 + tx * 4];
      const float wv[8] = {wl.x, wl.y, wl.z, wl.w, wh.x, wh.y, wh.z, wh.w};
      const float av[8] = {al.x, al.y, al.z, al.w, ah.x, ah.y, ah.z, ah.w};
#pragma unroll
      for (int jr = 0; jr < 8; ++jr)
#pragma unroll
        for (int bc = 0; bc < 8; ++bc)
          acc[jr][bc] = fmaf(wv[jr], av[bc], acc[jr][bc]);
    }
    if (t < 63) {
      const int nxt = cur ^ 1;
#pragma unroll
      for (int i = 0; i < 4; ++i) Wt[nxt][wk0 + i][wj] = ((const float*)&wr0)[i];
#pragma unroll
      for (int i = 0; i < 4; ++i)
        Wt[nxt][wk0 + 4 + i][wj] = ((const float*)&wr1)[i];
      *(float4*)&At[nxt][ak][ab] = ar0;
      *(float4*)&At[nxt][ak][ab + 4] = ar1;
    }
    __syncthreads();
  }

#pragma unroll
  for (int jr = 0; jr < 8; ++jr) {
    const int j = j0 + (jr < 4 ? ty * 4 + jr : 64 + ty * 4 + (jr - 4));
    const float bj = fb1[j];
    float4 lo, hi;
    lo.x = fmaxf(acc[jr][0] + bj, 0.f);
    lo.y = fmaxf(acc[jr][1] + bj, 0.f);
    lo.z = fmaxf(acc[jr][2] + bj, 0.f);
    lo.w = fmaxf(acc[jr][3] + bj, 0.f);
    hi.x = fmaxf(acc[jr][4] + bj, 0.f);
    hi.y = fmaxf(acc[jr][5] + bj, 0.f);
    hi.z = fmaxf(acc[jr][6] + bj, 0.f);
    hi.w = fmaxf(acc[jr][7] + bj, 0.f);
    *(float4*)&out[(size_t)j * B + b0 + tx * 4] = lo;
    *(float4*)&out[(size_t)j * B + b0 + 64 + tx * 4] = hi;
  }
}

// ---------------- FC2: out[b,10] = fw2[10,512] @ h4[512,B] + fb2 -----------
__global__ __launch_bounds__(256) void k_fc2(const float* __restrict__ in,
                                             const float* __restrict__ fw2,
                                             const float* __restrict__ fb2,
                                             float* __restrict__ out, int B,
                                             int b0) {
  __shared__ float red[4][10][64];
  const int tx = threadIdx.x;
  const int b = blockIdx.x * 64 + tx;
  const int tyu = threadIdx.y;
  float acc[10];
#pragma unroll
  for (int i = 0; i < 10; ++i) acc[i] = 0.f;
  for (int kk = 0; kk < 128; ++kk) {
    const int k = tyu * 128 + kk;
    const float v = in[(size_t)k * B + b];
#pragma unroll
    for (int i = 0; i < 10; ++i) acc[i] = fmaf(v, fw2[i * 512 + k], acc[i]);
  }
#pragma unroll
  for (int i = 0; i < 10; ++i) red[tyu][i][tx] = acc[i];
  __syncthreads();
  if (threadIdx.y == 0) {
#pragma unroll
    for (int i = 0; i < 10; ++i) {
      const float s = fb2[i] + red[0][i][tx] + red[1][i][tx] + red[2][i][tx] +
                      red[3][i][tx];
      out[(size_t)(b0 + b) * 10 + i] = s;
    }
  }
}

extern "C" void kernel_launch(void* const* d_in, const int* in_sizes, int n_in,
                              void* d_out, int out_size, void* d_ws,
                              size_t ws_size, hipStream_t stream) {
  const float* x   = (const float*)d_in[0];
  const float* w1  = (const float*)d_in[1];
  const float* b1  = (const float*)d_in[2];
  const float* w2  = (const float*)d_in[3];
  const float* b2  = (const float*)d_in[4];
  const float* w3  = (const float*)d_in[5];
  const float* b3  = (const float*)d_in[6];
  const float* fw1 = (const float*)d_in[7];
  const float* fb1 = (const float*)d_in[8];
  const float* fw2 = (const float*)d_in[9];
  const float* fb2 = (const float*)d_in[10];
  float* out = (float*)d_out;

  const int B = in_sizes[0] / 784;  // 8192

  const size_t per_elem = (size_t)(784 + 2704 + 1152) * sizeof(float);
  int Bc = B;
  while ((size_t)Bc * per_elem > ws_size && Bc > 512) Bc >>= 1;
  const int nch = B / Bc;

  float* P0 = (float*)d_ws;              // xT[784,Bc] then h4[512,Bc]
  float* P1 = P0 + (size_t)784 * Bc;     // h1[2704,Bc] then h3[1024,Bc]
  float* P2 = P1 + (size_t)2704 * Bc;    // h2[1152,Bc]

  for (int ch = 0; ch < nch; ++ch) {
    const float* xc = x + (size_t)ch * Bc * 784;
    const int b0 = ch * Bc;
    const int nb = Bc / 64;

    k_tr<<<dim3(Bc / 32, 25), dim3(32, 8), 0, stream>>>(xc, P0, Bc);
    k_lc1<<<dim3(nb, 13), dim3(64, 4), 0, stream>>>(P0, w1, b1, P1, Bc);
    k_lc2<<<dim3(nb, 8), dim3(64, 4), 0, stream>>>(P1, w2, b2, P2, Bc);
    k_lc3<<<dim3(nb, 8), dim3(64, 4), 0, stream>>>(P2, w3, b3, P1, Bc);
    k_fc1<<<dim3(Bc / 128, 4), dim3(256), 0, stream>>>(P1, fw1, fb1, P0, Bc);
    k_fc2<<<dim3(nb), dim3(64, 4), 0, stream>>>(P0, fw2, fb2, out, Bc, b0);
  }
}

// Round 6
// 857.688 us; speedup vs baseline: 1.0718x; 1.0718x over previous
//
#include <hip/hip_runtime.h>

// Activations in batch-last layout [feature, B]; lanes = batch (coalesced).

// ---------------- transpose x[B,784] -> xT[784, Bc] ----------------
__global__ __launch_bounds__(256) void k_tr(const float* __restrict__ x,
                                            float* __restrict__ xT, int Bc) {
  __shared__ float t[32][33];
  const int b0 = blockIdx.x * 32;
  const int f0 = blockIdx.y * 32;
  const int tx = threadIdx.x, ty = threadIdx.y;
  for (int r = ty; r < 32; r += 8) {
    const int f = f0 + tx;
    t[r][tx] = (f < 784) ? x[(size_t)(b0 + r) * 784 + f] : 0.f;
  }
  __syncthreads();
  for (int r = ty; r < 32; r += 8) {
    const int f = f0 + r;
    if (f < 784) xT[(size_t)f * Bc + b0 + tx] = t[tx][r];
  }
}

// ---------------- LC1: [1,28,28] -> [16,13,13], stride 2, relu -------------
__global__ __launch_bounds__(256) void k_lc1(const float* __restrict__ in,
                                             const float* __restrict__ w,
                                             const float* __restrict__ bias,
                                             float* __restrict__ out, int B) {
  const int b = blockIdx.x * 64 + threadIdx.x;
  const int ho = blockIdx.y;
  const int o0 = threadIdx.y * 4;
  float xv[3][27];
#pragma unroll
  for (int r = 0; r < 3; ++r)
#pragma unroll
    for (int col = 0; col < 27; ++col)
      xv[r][col] = in[(size_t)((2 * ho + r) * 28 + col) * B + b];
  float acc[4][13];
#pragma unroll
  for (int oo = 0; oo < 4; ++oo)
#pragma unroll
    for (int wo = 0; wo < 13; ++wo)
      acc[oo][wo] = bias[(o0 + oo) * 169 + ho * 13 + wo];
#pragma unroll
  for (int oo = 0; oo < 4; ++oo)
#pragma unroll
    for (int wo = 0; wo < 13; ++wo) {
      const float* wp = w + (size_t)((o0 + oo) * 169 + ho * 13 + wo) * 9;
#pragma unroll
      for (int kh = 0; kh < 3; ++kh)
#pragma unroll
        for (int kw = 0; kw < 3; ++kw)
          acc[oo][wo] = fmaf(xv[kh][2 * wo + kw], wp[kh * 3 + kw], acc[oo][wo]);
    }
#pragma unroll
  for (int oo = 0; oo < 4; ++oo)
#pragma unroll
    for (int wo = 0; wo < 13; ++wo)
      out[(size_t)((o0 + oo) * 169 + ho * 13 + wo) * B + b] =
          fmaxf(acc[oo][wo], 0.f);
}

// ---------------- LC2: [16,13,13] -> [32,6,6], stride 2, relu --------------
// grid (B/128, 16 = oblk*2+hh), block (64,4). Wave = 1 o; lane = 2 batches.
// Per c: stage 7x13x128 (46.6 KB) pipelined; rolling 3-row x 7-col window,
// wo split into halves {0..2},{3..5}. Each w float feeds 2 FMA instrs.
#define LC2_LOADR(dst, r)                                              \
  _Pragma("unroll") for (int col = 0; col < 7; ++col)                  \
      dst[col] = *(const float2*)&Xs[(((r)*13) + c0 + col) * 128 + 2 * lane];

#define LC2_COMP(hl, R0, R1, R2)                                       \
  _Pragma("unroll") for (int wl = 0; wl < 3; ++wl) {                   \
    const int wo = half * 3 + wl;                                      \
    const float* wq = wp + ((hl)*6 + wo) * 9;                          \
    float a0 = acc[(hl)*6 + wo][0], a1 = acc[(hl)*6 + wo][1];          \
    _Pragma("unroll") for (int kw = 0; kw < 3; ++kw) {                 \
      const float w0 = wq[kw], w1 = wq[3 + kw], w2 = wq[6 + kw];       \
      a0 = fmaf(R0[2 * wl + kw].x, w0, a0);                            \
      a1 = fmaf(R0[2 * wl + kw].y, w0, a1);                            \
      a0 = fmaf(R1[2 * wl + kw].x, w1, a0);                            \
      a1 = fmaf(R1[2 * wl + kw].y, w1, a1);                            \
      a0 = fmaf(R2[2 * wl + kw].x, w2, a0);                            \
      a1 = fmaf(R2[2 * wl + kw].y, w2, a1);                            \
    }                                                                  \
    acc[(hl)*6 + wo][0] = a0;                                          \
    acc[(hl)*6 + wo][1] = a1;                                          \
  }

__global__ __launch_bounds__(256) void k_lc2(const float* __restrict__ in,
                                             const float* __restrict__ w,
                                             const float* __restrict__ bias,
                                             float* __restrict__ out, int B) {
  __shared__ float Xs[7 * 13 * 128];
  const int lane = threadIdx.x;
  const int wv = threadIdx.y;
  const int tid = wv * 64 + lane;
  const int b0 = blockIdx.x * 128;
  const int oblk = blockIdx.y >> 1, hh = blockIdx.y & 1;
  const int o = oblk * 4 + wv;
  const int row0 = hh * 6;
  const size_t cstep = (size_t)169 * B;

  float acc[18][2];
#pragma unroll
  for (int p = 0; p < 18; ++p) {
    const float bz = bias[o * 36 + hh * 18 + p];
    acc[p][0] = bz;
    acc[p][1] = bz;
  }

  // staging map: f4 in [0,2912): row=f4/416, col=(f4%416)>>5, bq=f4&31
  unsigned off[12];
  bool ok[12];
#pragma unroll
  for (int i = 0; i < 12; ++i) {
    const int f4 = tid + i * 256;
    ok[i] = f4 < 2912;
    const int row = f4 / 416;
    const int rem = f4 - row * 416;
    const int col = rem >> 5, bq = rem & 31;
    off[i] = (unsigned)(((row0 + row) * 13 + col) * B + b0 + bq * 4);
  }

  float4 v[12];
#pragma unroll
  for (int i = 0; i < 12; ++i)
    if (ok[i]) v[i] = *(const float4*)&in[off[i]];

#pragma unroll 1
  for (int c = 0; c < 16; ++c) {
    __syncthreads();
#pragma unroll
    for (int i = 0; i < 12; ++i)
      if (ok[i]) *(float4*)&Xs[(tid + i * 256) * 4] = v[i];
    __syncthreads();
    if (c < 15) {
      const float* nin = in + (size_t)(c + 1) * cstep;
#pragma unroll
      for (int i = 0; i < 12; ++i)
        if (ok[i]) v[i] = *(const float4*)&nin[off[i]];
    }
    const float* wp = w + ((size_t)o * 16 + c) * 36 * 9 + hh * 18 * 9;
#pragma unroll
    for (int half = 0; half < 2; ++half) {
      const int c0 = half * 6;
      float2 RA[7], RB[7], RC[7];
      LC2_LOADR(RA, 0) LC2_LOADR(RB, 1) LC2_LOADR(RC, 2)
      LC2_COMP(0, RA, RB, RC)
      LC2_LOADR(RA, 3) LC2_LOADR(RB, 4)
      LC2_COMP(1, RC, RA, RB)
      LC2_LOADR(RC, 5) LC2_LOADR(RA, 6)
      LC2_COMP(2, RB, RC, RA)
    }
  }
#pragma unroll
  for (int p = 0; p < 18; ++p) {
    float2 r;
    r.x = fmaxf(acc[p][0], 0.f);
    r.y = fmaxf(acc[p][1], 0.f);
    *(float2*)&out[(size_t)(o * 36 + hh * 18 + p) * B + b0 + 2 * lane] = r;
  }
}

// ---------------- LC3: [32,6,6] -> [64,4,4], stride 1, no relu -------------
// grid (B/128, 16 oblk), block (64,4). Wave = 1 o; lane = 2 batches.
// Per c: stage 6x6x128 (18.4 KB) pipelined; rolling 4-row window.
#define LC3_LOADR(dst, r)                                              \
  _Pragma("unroll") for (int col = 0; col < 6; ++col)                  \
      dst[col] = *(const float2*)&Xs[((r)*6 + col) * 128 + 2 * lane];

#define LC3_COMP(ho, R0, R1, R2)                                       \
  _Pragma("unroll") for (int wo = 0; wo < 4; ++wo) {                   \
    const float* wq = wp + ((ho)*4 + wo) * 9;                          \
    float a0 = acc[(ho)*4 + wo][0], a1 = acc[(ho)*4 + wo][1];          \
    _Pragma("unroll") for (int kw = 0; kw < 3; ++kw) {                 \
      const float w0 = wq[kw], w1 = wq[3 + kw], w2 = wq[6 + kw];       \
      a0 = fmaf(R0[wo + kw].x, w0, a0);                                \
      a1 = fmaf(R0[wo + kw].y, w0, a1);                                \
      a0 = fmaf(R1[wo + kw].x, w1, a0);                                \
      a1 = fmaf(R1[wo + kw].y, w1, a1);                                \
      a0 = fmaf(R2[wo + kw].x, w2, a0);                                \
      a1 = fmaf(R2[wo + kw].y, w2, a1);                                \
    }                                                                  \
    acc[(ho)*4 + wo][0] = a0;                                          \
    acc[(ho)*4 + wo][1] = a1;                                          \
  }

__global__ __launch_bounds__(256) void k_lc3(const float* __restrict__ in,
                                             const float* __restrict__ w,
                                             const float* __restrict__ bias,
                                             float* __restrict__ out, int B) {
  __shared__ float Xs[36 * 128];
  const int lane = threadIdx.x;
  const int wv = threadIdx.y;
  const int tid = wv * 64 + lane;
  const int b0 = blockIdx.x * 128;
  const int o = blockIdx.y * 4 + wv;
  const size_t cstep = (size_t)36 * B;

  float acc[16][2];
#pragma unroll
  for (int p = 0; p < 16; ++p) {
    const float bz = bias[o * 16 + p];
    acc[p][0] = bz;
    acc[p][1] = bz;
  }

  unsigned off[5];
  bool ok[5];
#pragma unroll
  for (int i = 0; i < 5; ++i) {
    const int f4 = tid + i * 256;
    ok[i] = f4 < 1152;
    const int pos = f4 >> 5, bq = f4 & 31;
    off[i] = (unsigned)(pos * B + b0 + bq * 4);
  }

  float4 v[5];
#pragma unroll
  for (int i = 0; i < 5; ++i)
    if (ok[i]) v[i] = *(const float4*)&in[off[i]];

#pragma unroll 1
  for (int c = 0; c < 32; ++c) {
    __syncthreads();
#pragma unroll
    for (int i = 0; i < 5; ++i)
      if (ok[i]) *(float4*)&Xs[(tid + i * 256) * 4] = v[i];
    __syncthreads();
    if (c < 31) {
      const float* nin = in + (size_t)(c + 1) * cstep;
#pragma unroll
      for (int i = 0; i < 5; ++i)
        if (ok[i]) v[i] = *(const float4*)&nin[off[i]];
    }
    const float* wp = w + ((size_t)o * 32 + c) * 16 * 9;
    float2 RA[6], RB[6], RC[6], RD[6];
    LC3_LOADR(RA, 0) LC3_LOADR(RB, 1) LC3_LOADR(RC, 2) LC3_LOADR(RD, 3)
    LC3_COMP(0, RA, RB, RC)
    LC3_COMP(1, RB, RC, RD)
    LC3_LOADR(RA, 4) LC3_LOADR(RB, 5)
    LC3_COMP(2, RC, RD, RA)
    LC3_COMP(3, RD, RA, RB)
  }
#pragma unroll
  for (int p = 0; p < 16; ++p) {
    float2 r;
    r.x = acc[p][0];
    r.y = acc[p][1];
    *(float2*)&out[(size_t)(o * 16 + p) * B + b0 + 2 * lane] = r;
  }
}

// ---------------- FC1: SGEMM h4[512,B] = relu(fw1[512,1024] @ h3[1024,B]) --
__global__ __launch_bounds__(256) void k_fc1(const float* __restrict__ in,
                                             const float* __restrict__ fw1,
                                             const float* __restrict__ fb1,
                                             float* __restrict__ out, int B) {
  __shared__ float Wt[2][16][128];
  __shared__ float At[2][16][128];
  const int tid = threadIdx.x;
  const int tx = tid & 15, ty = tid >> 4;
  const int b0 = blockIdx.x * 128, j0 = blockIdx.y * 128;
  const int wj = tid >> 1, wk0 = (tid & 1) * 8;
  const int ak = tid >> 4, ab = (tid & 15) * 8;
  const float* wsrc = fw1 + (size_t)(j0 + wj) * 1024 + wk0;
  const float* asrc = in + (size_t)ak * B + b0 + ab;

  float4 wr0 = *(const float4*)(wsrc);
  float4 wr1 = *(const float4*)(wsrc + 4);
  float4 ar0 = *(const float4*)(asrc);
  float4 ar1 = *(const float4*)(asrc + 4);

  float acc[8][8];
#pragma unroll
  for (int jr = 0; jr < 8; ++jr)
#pragma unroll
    for (int bc = 0; bc < 8; ++bc) acc[jr][bc] = 0.f;

#pragma unroll
  for (int i = 0; i < 4; ++i) Wt[0][wk0 + i][wj] = ((const float*)&wr0)[i];
#pragma unroll
  for (int i = 0; i < 4; ++i) Wt[0][wk0 + 4 + i][wj] = ((const float*)&wr1)[i];
  *(float4*)&At[0][ak][ab] = ar0;
  *(float4*)&At[0][ak][ab + 4] = ar1;
  __syncthreads();

  for (int t = 0; t < 64; ++t) {
    const int cur = t & 1;
    if (t < 63) {
      const float* wp = wsrc + (t + 1) * 16;
      wr0 = *(const float4*)(wp);
      wr1 = *(const float4*)(wp + 4);
      const float* ap = asrc + (size_t)(t + 1) * 16 * B;
      ar0 = *(const float4*)(ap);
      ar1 = *(const float4*)(ap + 4);
    }
#pragma unroll
    for (int k = 0; k < 16; ++k) {
      float4 wl = *(const float4*)&Wt[cur][k][ty * 4];
      float4 wh = *(const float4*)&Wt[cur][k][64 + ty * 4];
      float4 al = *(const float4*)&At[cur][k][tx * 4];
      float4 ah = *(const float4*)&At[cur][k][64 + tx * 4];
      const float wv[8] = {wl.x, wl.y, wl.z, wl.w, wh.x, wh.y, wh.z, wh.w};
      const float av[8] = {al.x, al.y, al.z, al.w, ah.x, ah.y, ah.z, ah.w};
#pragma unroll
      for (int jr = 0; jr < 8; ++jr)
#pragma unroll
        for (int bc = 0; bc < 8; ++bc)
          acc[jr][bc] = fmaf(wv[jr], av[bc], acc[jr][bc]);
    }
    if (t < 63) {
      const int nxt = cur ^ 1;
#pragma unroll
      for (int i = 0; i < 4; ++i) Wt[nxt][wk0 + i][wj] = ((const float*)&wr0)[i];
#pragma unroll
      for (int i = 0; i < 4; ++i)
        Wt[nxt][wk0 + 4 + i][wj] = ((const float*)&wr1)[i];
      *(float4*)&At[nxt][ak][ab] = ar0;
      *(float4*)&At[nxt][ak][ab + 4] = ar1;
    }
    __syncthreads();
  }

#pragma unroll
  for (int jr = 0; jr < 8; ++jr) {
    const int j = j0 + (jr < 4 ? ty * 4 + jr : 64 + ty * 4 + (jr - 4));
    const float bj = fb1[j];
    float4 lo, hi;
    lo.x = fmaxf(acc[jr][0] + bj, 0.f);
    lo.y = fmaxf(acc[jr][1] + bj, 0.f);
    lo.z = fmaxf(acc[jr][2] + bj, 0.f);
    lo.w = fmaxf(acc[jr][3] + bj, 0.f);
    hi.x = fmaxf(acc[jr][4] + bj, 0.f);
    hi.y = fmaxf(acc[jr][5] + bj, 0.f);
    hi.z = fmaxf(acc[jr][6] + bj, 0.f);
    hi.w = fmaxf(acc[jr][7] + bj, 0.f);
    *(float4*)&out[(size_t)j * B + b0 + tx * 4] = lo;
    *(float4*)&out[(size_t)j * B + b0 + 64 + tx * 4] = hi;
  }
}

// ---------------- FC2: out[b,10] = fw2[10,512] @ h4[512,B] + fb2 -----------
__global__ __launch_bounds__(256) void k_fc2(const float* __restrict__ in,
                                             const float* __restrict__ fw2,
                                             const float* __restrict__ fb2,
                                             float* __restrict__ out, int B,
                                             int b0) {
  __shared__ float red[4][10][64];
  const int tx = threadIdx.x;
  const int b = blockIdx.x * 64 + tx;
  const int tyu = threadIdx.y;
  float acc[10];
#pragma unroll
  for (int i = 0; i < 10; ++i) acc[i] = 0.f;
  for (int kk = 0; kk < 128; ++kk) {
    const int k = tyu * 128 + kk;
    const float v = in[(size_t)k * B + b];
#pragma unroll
    for (int i = 0; i < 10; ++i) acc[i] = fmaf(v, fw2[i * 512 + k], acc[i]);
  }
#pragma unroll
  for (int i = 0; i < 10; ++i) red[tyu][i][tx] = acc[i];
  __syncthreads();
  if (threadIdx.y == 0) {
#pragma unroll
    for (int i = 0; i < 10; ++i) {
      const float s = fb2[i] + red[0][i][tx] + red[1][i][tx] + red[2][i][tx] +
                      red[3][i][tx];
      out[(size_t)(b0 + b) * 10 + i] = s;
    }
  }
}

extern "C" void kernel_launch(void* const* d_in, const int* in_sizes, int n_in,
                              void* d_out, int out_size, void* d_ws,
                              size_t ws_size, hipStream_t stream) {
  const float* x   = (const float*)d_in[0];
  const float* w1  = (const float*)d_in[1];
  const float* b1  = (const float*)d_in[2];
  const float* w2  = (const float*)d_in[3];
  const float* b2  = (const float*)d_in[4];
  const float* w3  = (const float*)d_in[5];
  const float* b3  = (const float*)d_in[6];
  const float* fw1 = (const float*)d_in[7];
  const float* fb1 = (const float*)d_in[8];
  const float* fw2 = (const float*)d_in[9];
  const float* fb2 = (const float*)d_in[10];
  float* out = (float*)d_out;

  const int B = in_sizes[0] / 784;  // 8192

  const size_t per_elem = (size_t)(784 + 2704 + 1152) * sizeof(float);
  int Bc = B;
  while ((size_t)Bc * per_elem > ws_size && Bc > 512) Bc >>= 1;
  const int nch = B / Bc;

  float* P0 = (float*)d_ws;              // xT[784,Bc] then h4[512,Bc]
  float* P1 = P0 + (size_t)784 * Bc;     // h1[2704,Bc] then h3[1024,Bc]
  float* P2 = P1 + (size_t)2704 * Bc;    // h2[1152,Bc]

  for (int ch = 0; ch < nch; ++ch) {
    const float* xc = x + (size_t)ch * Bc * 784;
    const int b0 = ch * Bc;
    const int nb = Bc / 64;

    k_tr<<<dim3(Bc / 32, 25), dim3(32, 8), 0, stream>>>(xc, P0, Bc);
    k_lc1<<<dim3(nb, 13), dim3(64, 4), 0, stream>>>(P0, w1, b1, P1, Bc);
    k_lc2<<<dim3(Bc / 128, 16), dim3(64, 4), 0, stream>>>(P1, w2, b2, P2, Bc);
    k_lc3<<<dim3(Bc / 128, 16), dim3(64, 4), 0, stream>>>(P2, w3, b3, P1, Bc);
    k_fc1<<<dim3(Bc / 128, 4), dim3(256), 0, stream>>>(P1, fw1, fb1, P0, Bc);
    k_fc2<<<dim3(nb), dim3(64, 4), 0, stream>>>(P0, fw2, fb2, out, Bc, b0);
  }
}

// Round 7
// 322.700 us; speedup vs baseline: 2.8488x; 2.6579x over previous
//
#include <hip/hip_runtime.h>

// Activations in batch-last layout [feature, B]; lanes = batch (coalesced).

// ---------------- transpose x[B,784] -> xT[784, Bc] ----------------
__global__ __launch_bounds__(256) void k_tr(const float* __restrict__ x,
                                            float* __restrict__ xT, int Bc) {
  __shared__ float t[32][33];
  const int b0 = blockIdx.x * 32;
  const int f0 = blockIdx.y * 32;
  const int tx = threadIdx.x, ty = threadIdx.y;
  for (int r = ty; r < 32; r += 8) {
    const int f = f0 + tx;
    t[r][tx] = (f < 784) ? x[(size_t)(b0 + r) * 784 + f] : 0.f;
  }
  __syncthreads();
  for (int r = ty; r < 32; r += 8) {
    const int f = f0 + r;
    if (f < 784) xT[(size_t)f * Bc + b0 + tx] = t[tx][r];
  }
}

// ---------------- LC1: [1,28,28] -> [16,13,13], stride 2, relu -------------
__global__ __launch_bounds__(256) void k_lc1(const float* __restrict__ in,
                                             const float* __restrict__ w,
                                             const float* __restrict__ bias,
                                             float* __restrict__ out, int B) {
  const int b = blockIdx.x * 64 + threadIdx.x;
  const int ho = blockIdx.y;
  const int o0 = threadIdx.y * 4;
  float xv[3][27];
#pragma unroll
  for (int r = 0; r < 3; ++r)
#pragma unroll
    for (int col = 0; col < 27; ++col)
      xv[r][col] = in[(size_t)((2 * ho + r) * 28 + col) * B + b];
  float acc[4][13];
#pragma unroll
  for (int oo = 0; oo < 4; ++oo)
#pragma unroll
    for (int wo = 0; wo < 13; ++wo)
      acc[oo][wo] = bias[(o0 + oo) * 169 + ho * 13 + wo];
#pragma unroll
  for (int oo = 0; oo < 4; ++oo)
#pragma unroll
    for (int wo = 0; wo < 13; ++wo) {
      const float* wp = w + (size_t)((o0 + oo) * 169 + ho * 13 + wo) * 9;
#pragma unroll
      for (int kh = 0; kh < 3; ++kh)
#pragma unroll
        for (int kw = 0; kw < 3; ++kw)
          acc[oo][wo] = fmaf(xv[kh][2 * wo + kw], wp[kh * 3 + kw], acc[oo][wo]);
    }
#pragma unroll
  for (int oo = 0; oo < 4; ++oo)
#pragma unroll
    for (int wo = 0; wo < 13; ++wo)
      out[(size_t)((o0 + oo) * 169 + ho * 13 + wo) * B + b] =
          fmaxf(acc[oo][wo], 0.f);
}

// ---------------- weight pre-transpose: wt[pos][k][o] = w[o][c][pos][kk] ---
template <int O, int C, int NPOS>
__global__ __launch_bounds__(256) void k_wt(const float* __restrict__ w,
                                            float* __restrict__ wt) {
  const int pos = blockIdx.x;
  const int k = blockIdx.y * blockDim.y + threadIdx.y;
  const int o = threadIdx.x;
  const int c = k / 9, kk = k - c * 9;
  wt[((size_t)pos * (C * 9) + k) * O + o] =
      w[((size_t)(o * C + c) * NPOS + pos) * 9 + kk];
}

// ---------------- generic LC layer as per-position SGEMM -------------------
// out[o*NPOS+pos, b0..b0+127] = Wt[pos] (K x O, col-major-in-o) ^T @ X-rows.
// block 256 thr = TO o-groups x TB b-groups; thread = 4 o x BPT b.
// Double-buffered KT=16 chunks; X rows gathered via LDS row table.
template <int O, int K, int NPOS, int HWIN, int WIN, int WOD, int STR,
          bool RELU>
__global__ __launch_bounds__(256) void k_lcg(const float* __restrict__ X,
                                             const float* __restrict__ Wt,
                                             const float* __restrict__ bias,
                                             float* __restrict__ out, int B) {
  constexpr int KT = 16;
  constexpr int TO = O / 4;      // o-groups (LC3:16, LC2:8)
  constexpr int TB = 256 / TO;   // b-groups (LC3:16, LC2:32)
  constexpr int BPT = 128 / TB;  // b per thread (LC3:8, LC2:4)
  constexpr int NSTEP = K / KT;
  constexpr int WF4 = KT * O / 4;  // W float4s per chunk (LC3:256, LC2:128)
  __shared__ float Xs[2][KT][128];
  __shared__ float Ws[2][KT][O];
  __shared__ int rowtab[K];
  const int tid = threadIdx.x;
  const int b0 = blockIdx.x * 128;
  const int pos = blockIdx.y;
  const int ho = pos / WOD, wo = pos - ho * WOD;

  for (int k = tid; k < K; k += 256) {
    const int c = k / 9, kk = k - c * 9;
    const int kh = kk / 3, kw = kk - kh * 3;
    rowtab[k] = c * HWIN + (ho * STR + kh) * WIN + (wo * STR + kw);
  }
  __syncthreads();

  const float* wsrc = Wt + (size_t)pos * K * O;
  const int xr0 = tid >> 5, xq0 = (tid & 31) * 4;
  const int xr1 = (tid + 256) >> 5, xq1 = ((tid + 256) & 31) * 4;
  const int wr = tid / (O / 4), wc = (tid % (O / 4)) * 4;
  const int to = tid % TO, tb = tid / TO;

  float4 xv0, xv1, wv0;
  xv0 = *(const float4*)&X[(size_t)rowtab[xr0] * B + b0 + xq0];
  xv1 = *(const float4*)&X[(size_t)rowtab[xr1] * B + b0 + xq1];
  if (WF4 == 256 || tid < WF4) wv0 = *(const float4*)&wsrc[tid * 4];

  float acc[4][BPT];
#pragma unroll
  for (int oo = 0; oo < 4; ++oo)
#pragma unroll
    for (int bb = 0; bb < BPT; ++bb) acc[oo][bb] = 0.f;

  *(float4*)&Xs[0][xr0][xq0] = xv0;
  *(float4*)&Xs[0][xr1][xq1] = xv1;
  if (WF4 == 256 || tid < WF4) *(float4*)&Ws[0][wr][wc] = wv0;
  __syncthreads();

  for (int t = 0; t < NSTEP; ++t) {
    const int cur = t & 1;
    if (t < NSTEP - 1) {
      const int k0 = (t + 1) * KT;
      xv0 = *(const float4*)&X[(size_t)rowtab[k0 + xr0] * B + b0 + xq0];
      xv1 = *(const float4*)&X[(size_t)rowtab[k0 + xr1] * B + b0 + xq1];
      if (WF4 == 256 || tid < WF4)
        wv0 = *(const float4*)&wsrc[(size_t)k0 * O + tid * 4];
    }
#pragma unroll
    for (int k = 0; k < KT; ++k) {
      const float4 w4 = *(const float4*)&Ws[cur][k][to * 4];
#pragma unroll
      for (int q = 0; q < BPT / 4; ++q) {
        const float4 x4 = *(const float4*)&Xs[cur][k][tb * BPT + q * 4];
        const float xs[4] = {x4.x, x4.y, x4.z, x4.w};
        const float ws4[4] = {w4.x, w4.y, w4.z, w4.w};
#pragma unroll
        for (int oo = 0; oo < 4; ++oo)
#pragma unroll
          for (int j = 0; j < 4; ++j)
            acc[oo][q * 4 + j] = fmaf(ws4[oo], xs[j], acc[oo][q * 4 + j]);
      }
    }
    if (t < NSTEP - 1) {
      const int nxt = cur ^ 1;
      *(float4*)&Xs[nxt][xr0][xq0] = xv0;
      *(float4*)&Xs[nxt][xr1][xq1] = xv1;
      if (WF4 == 256 || tid < WF4) *(float4*)&Ws[nxt][wr][wc] = wv0;
    }
    __syncthreads();
  }

#pragma unroll
  for (int oo = 0; oo < 4; ++oo) {
    const int f = (to * 4 + oo) * NPOS + pos;
    const float bz = bias[f];
#pragma unroll
    for (int q = 0; q < BPT / 4; ++q) {
      float4 r;
      r.x = acc[oo][q * 4 + 0] + bz;
      r.y = acc[oo][q * 4 + 1] + bz;
      r.z = acc[oo][q * 4 + 2] + bz;
      r.w = acc[oo][q * 4 + 3] + bz;
      if (RELU) {
        r.x = fmaxf(r.x, 0.f);
        r.y = fmaxf(r.y, 0.f);
        r.z = fmaxf(r.z, 0.f);
        r.w = fmaxf(r.w, 0.f);
      }
      *(float4*)&out[(size_t)f * B + b0 + tb * BPT + q * 4] = r;
    }
  }
}

// ---------------- FC1: SGEMM h4[512,B] = relu(fw1[512,1024] @ h3[1024,B]) --
__global__ __launch_bounds__(256) void k_fc1(const float* __restrict__ in,
                                             const float* __restrict__ fw1,
                                             const float* __restrict__ fb1,
                                             float* __restrict__ out, int B) {
  __shared__ float Wt[2][16][128];
  __shared__ float At[2][16][128];
  const int tid = threadIdx.x;
  const int tx = tid & 15, ty = tid >> 4;
  const int b0 = blockIdx.x * 128, j0 = blockIdx.y * 128;
  const int wj = tid >> 1, wk0 = (tid & 1) * 8;
  const int ak = tid >> 4, ab = (tid & 15) * 8;
  const float* wsrc = fw1 + (size_t)(j0 + wj) * 1024 + wk0;
  const float* asrc = in + (size_t)ak * B + b0 + ab;

  float4 wr0 = *(const float4*)(wsrc);
  float4 wr1 = *(const float4*)(wsrc + 4);
  float4 ar0 = *(const float4*)(asrc);
  float4 ar1 = *(const float4*)(asrc + 4);

  float acc[8][8];
#pragma unroll
  for (int jr = 0; jr < 8; ++jr)
#pragma unroll
    for (int bc = 0; bc < 8; ++bc) acc[jr][bc] = 0.f;

#pragma unroll
  for (int i = 0; i < 4; ++i) Wt[0][wk0 + i][wj] = ((const float*)&wr0)[i];
#pragma unroll
  for (int i = 0; i < 4; ++i) Wt[0][wk0 + 4 + i][wj] = ((const float*)&wr1)[i];
  *(float4*)&At[0][ak][ab] = ar0;
  *(float4*)&At[0][ak][ab + 4] = ar1;
  __syncthreads();

  for (int t = 0; t < 64; ++t) {
    const int cur = t & 1;
    if (t < 63) {
      const float* wp = wsrc + (t + 1) * 16;
      wr0 = *(const float4*)(wp);
      wr1 = *(const float4*)(wp + 4);
      const float* ap = asrc + (size_t)(t + 1) * 16 * B;
      ar0 = *(const float4*)(ap);
      ar1 = *(const float4*)(ap + 4);
    }
#pragma unroll
    for (int k = 0; k < 16; ++k) {
      float4 wl = *(const float4*)&Wt[cur][k][ty * 4];
      float4 wh = *(const float4*)&Wt[cur][k][64 + ty * 4];
      float4 al = *(const float4*)&At[cur][k][tx * 4];
      float4 ah = *(const float4*)&At[cur][k][64 + tx * 4];
      const float wv[8] = {wl.x, wl.y, wl.z, wl.w, wh.x, wh.y, wh.z, wh.w};
      const float av[8] = {al.x, al.y, al.z, al.w, ah.x, ah.y, ah.z, ah.w};
#pragma unroll
      for (int jr = 0; jr < 8; ++jr)
#pragma unroll
        for (int bc = 0; bc < 8; ++bc)
          acc[jr][bc] = fmaf(wv[jr], av[bc], acc[jr][bc]);
    }
    if (t < 63) {
      const int nxt = cur ^ 1;
#pragma unroll
      for (int i = 0; i < 4; ++i) Wt[nxt][wk0 + i][wj] = ((const float*)&wr0)[i];
#pragma unroll
      for (int i = 0; i < 4; ++i)
        Wt[nxt][wk0 + 4 + i][wj] = ((const float*)&wr1)[i];
      *(float4*)&At[nxt][ak][ab] = ar0;
      *(float4*)&At[nxt][ak][ab + 4] = ar1;
    }
    __syncthreads();
  }

#pragma unroll
  for (int jr = 0; jr < 8; ++jr) {
    const int j = j0 + (jr < 4 ? ty * 4 + jr : 64 + ty * 4 + (jr - 4));
    const float bj = fb1[j];
    float4 lo, hi;
    lo.x = fmaxf(acc[jr][0] + bj, 0.f);
    lo.y = fmaxf(acc[jr][1] + bj, 0.f);
    lo.z = fmaxf(acc[jr][2] + bj, 0.f);
    lo.w = fmaxf(acc[jr][3] + bj, 0.f);
    hi.x = fmaxf(acc[jr][4] + bj, 0.f);
    hi.y = fmaxf(acc[jr][5] + bj, 0.f);
    hi.z = fmaxf(acc[jr][6] + bj, 0.f);
    hi.w = fmaxf(acc[jr][7] + bj, 0.f);
    *(float4*)&out[(size_t)j * B + b0 + tx * 4] = lo;
    *(float4*)&out[(size_t)j * B + b0 + 64 + tx * 4] = hi;
  }
}

// ---------------- FC2: out[b,10] = fw2[10,512] @ h4[512,B] + fb2 -----------
__global__ __launch_bounds__(256) void k_fc2(const float* __restrict__ in,
                                             const float* __restrict__ fw2,
                                             const float* __restrict__ fb2,
                                             float* __restrict__ out, int B,
                                             int b0) {
  __shared__ float red[4][10][64];
  const int tx = threadIdx.x;
  const int b = blockIdx.x * 64 + tx;
  const int tyu = threadIdx.y;
  float acc[10];
#pragma unroll
  for (int i = 0; i < 10; ++i) acc[i] = 0.f;
  for (int kk = 0; kk < 128; ++kk) {
    const int k = tyu * 128 + kk;
    const float v = in[(size_t)k * B + b];
#pragma unroll
    for (int i = 0; i < 10; ++i) acc[i] = fmaf(v, fw2[i * 512 + k], acc[i]);
  }
#pragma unroll
  for (int i = 0; i < 10; ++i) red[tyu][i][tx] = acc[i];
  __syncthreads();
  if (threadIdx.y == 0) {
#pragma unroll
    for (int i = 0; i < 10; ++i) {
      const float s = fb2[i] + red[0][i][tx] + red[1][i][tx] + red[2][i][tx] +
                      red[3][i][tx];
      out[(size_t)(b0 + b) * 10 + i] = s;
    }
  }
}

extern "C" void kernel_launch(void* const* d_in, const int* in_sizes, int n_in,
                              void* d_out, int out_size, void* d_ws,
                              size_t ws_size, hipStream_t stream) {
  const float* x   = (const float*)d_in[0];
  const float* w1  = (const float*)d_in[1];
  const float* b1  = (const float*)d_in[2];
  const float* w2  = (const float*)d_in[3];
  const float* b2  = (const float*)d_in[4];
  const float* w3  = (const float*)d_in[5];
  const float* b3  = (const float*)d_in[6];
  const float* fw1 = (const float*)d_in[7];
  const float* fb1 = (const float*)d_in[8];
  const float* fw2 = (const float*)d_in[9];
  const float* fb2 = (const float*)d_in[10];
  float* out = (float*)d_out;

  const int B = in_sizes[0] / 784;  // 8192

  // ws: Wt2[36*144*32] | Wt3[16*288*64] | per-chunk {xT/h4, h1/h3, h2}
  const size_t nWt2 = (size_t)36 * 144 * 32;   // 165888
  const size_t nWt3 = (size_t)16 * 288 * 64;   // 294912
  float* Wt2 = (float*)d_ws;
  float* Wt3 = Wt2 + nWt2;
  float* base = Wt3 + nWt3;
  const size_t ws_rem = ws_size - (nWt2 + nWt3) * sizeof(float);

  const size_t per_elem = (size_t)(784 + 2704 + 1152) * sizeof(float);
  int Bc = B;
  while ((size_t)Bc * per_elem > ws_rem && Bc > 512) Bc >>= 1;
  const int nch = B / Bc;

  float* P0 = base;                      // xT[784,Bc] then h4[512,Bc]
  float* P1 = P0 + (size_t)784 * Bc;     // h1[2704,Bc] then h3[1024,Bc]
  float* P2 = P1 + (size_t)2704 * Bc;    // h2[1152,Bc]

  // one-time weight transposes (graph-safe: plain kernels, deterministic)
  k_wt<32, 16, 36><<<dim3(36, 36), dim3(32, 4), 0, stream>>>(w2, Wt2);
  k_wt<64, 32, 16><<<dim3(16, 72), dim3(64, 4), 0, stream>>>(w3, Wt3);

  for (int ch = 0; ch < nch; ++ch) {
    const float* xc = x + (size_t)ch * Bc * 784;
    const int b0 = ch * Bc;
    const int nb = Bc / 64;

    k_tr<<<dim3(Bc / 32, 25), dim3(32, 8), 0, stream>>>(xc, P0, Bc);
    k_lc1<<<dim3(nb, 13), dim3(64, 4), 0, stream>>>(P0, w1, b1, P1, Bc);
    // LC2: X=h1[2704,Bc] (C=16,13x13) -> h2[1152,Bc]; 36 positions
    k_lcg<32, 144, 36, 169, 13, 6, 2, true>
        <<<dim3(Bc / 128, 36), dim3(256), 0, stream>>>(P1, Wt2, b2, P2, Bc);
    // LC3: X=h2[1152,Bc] (C=32,6x6) -> h3[1024,Bc]; 16 positions
    k_lcg<64, 288, 16, 36, 6, 4, 1, false>
        <<<dim3(Bc / 128, 16), dim3(256), 0, stream>>>(P2, Wt3, b3, P1, Bc);
    k_fc1<<<dim3(Bc / 128, 4), dim3(256), 0, stream>>>(P1, fw1, fb1, P0, Bc);
    k_fc2<<<dim3(nb), dim3(64, 4), 0, stream>>>(P0, fw2, fb2, out, Bc, b0);
  }
}

// Round 9
// 221.112 us; speedup vs baseline: 4.1577x; 1.4594x over previous
//
#include <hip/hip_runtime.h>

typedef __attribute__((ext_vector_type(8))) short short8v;   // 8 bf16
typedef __attribute__((ext_vector_type(4))) float f32x4;

static __device__ __forceinline__ unsigned short f2bf(float f) {
  union { float f; unsigned u; } v;
  v.f = f;
  const unsigned u = v.u;
  return (unsigned short)((u + 0x7FFF + ((u >> 16) & 1)) >> 16);  // RNE
}

// Activations in batch-last layout [feature, B]; lanes = batch (coalesced).

// ---------------- transpose x[B,784] -> xT[784, Bc] ----------------
__global__ __launch_bounds__(256) void k_tr(const float* __restrict__ x,
                                            float* __restrict__ xT, int Bc) {
  __shared__ float t[32][33];
  const int b0 = blockIdx.x * 32;
  const int f0 = blockIdx.y * 32;
  const int tx = threadIdx.x, ty = threadIdx.y;
  for (int r = ty; r < 32; r += 8) {
    const int f = f0 + tx;
    t[r][tx] = (f < 784) ? x[(size_t)(b0 + r) * 784 + f] : 0.f;
  }
  __syncthreads();
  for (int r = ty; r < 32; r += 8) {
    const int f = f0 + r;
    if (f < 784) xT[(size_t)f * Bc + b0 + tx] = t[tx][r];
  }
}

// ---------------- LC1: [1,28,28] -> [16,13,13], stride 2, relu -------------
__global__ __launch_bounds__(256) void k_lc1(const float* __restrict__ in,
                                             const float* __restrict__ w,
                                             const float* __restrict__ bias,
                                             float* __restrict__ out, int B) {
  const int b = blockIdx.x * 64 + threadIdx.x;
  const int ho = blockIdx.y;
  const int o0 = threadIdx.y * 4;
  float xv[3][27];
#pragma unroll
  for (int r = 0; r < 3; ++r)
#pragma unroll
    for (int col = 0; col < 27; ++col)
      xv[r][col] = in[(size_t)((2 * ho + r) * 28 + col) * B + b];
  float acc[4][13];
#pragma unroll
  for (int oo = 0; oo < 4; ++oo)
#pragma unroll
    for (int wo = 0; wo < 13; ++wo)
      acc[oo][wo] = bias[(o0 + oo) * 169 + ho * 13 + wo];
#pragma unroll
  for (int oo = 0; oo < 4; ++oo)
#pragma unroll
    for (int wo = 0; wo < 13; ++wo) {
      const float* wp = w + (size_t)((o0 + oo) * 169 + ho * 13 + wo) * 9;
#pragma unroll
      for (int kh = 0; kh < 3; ++kh)
#pragma unroll
        for (int kw = 0; kw < 3; ++kw)
          acc[oo][wo] = fmaf(xv[kh][2 * wo + kw], wp[kh * 3 + kw], acc[oo][wo]);
    }
#pragma unroll
  for (int oo = 0; oo < 4; ++oo)
#pragma unroll
    for (int wo = 0; wo < 13; ++wo)
      out[(size_t)((o0 + oo) * 169 + ho * 13 + wo) * B + b] =
          fmaxf(acc[oo][wo], 0.f);
}

// ---------------- weight pre-transpose: wt[pos][k][o] = w[o][c][pos][kk] ---
template <int O, int C, int NPOS>
__global__ __launch_bounds__(256) void k_wt(const float* __restrict__ w,
                                            float* __restrict__ wt) {
  const int pos = blockIdx.x;
  const int k = blockIdx.y * blockDim.y + threadIdx.y;
  const int o = threadIdx.x;
  const int c = k / 9, kk = k - c * 9;
  wt[((size_t)pos * (C * 9) + k) * O + o] =
      w[((size_t)(o * C + c) * NPOS + pos) * 9 + kk];
}

// ---------------- fw1 -> bf16 copy (once) ----------------------------------
__global__ __launch_bounds__(256) void k_wbf(const float* __restrict__ w,
                                             unsigned short* __restrict__ o) {
  const int i = (blockIdx.x * 256 + threadIdx.x) * 8;
  const float4 a = *(const float4*)&w[i];
  const float4 b = *(const float4*)&w[i + 4];
  short8v r;
  r[0] = (short)f2bf(a.x); r[1] = (short)f2bf(a.y);
  r[2] = (short)f2bf(a.z); r[3] = (short)f2bf(a.w);
  r[4] = (short)f2bf(b.x); r[5] = (short)f2bf(b.y);
  r[6] = (short)f2bf(b.z); r[7] = (short)f2bf(b.w);
  *(short8v*)&o[i] = r;
}

// ---------------- generic LC layer as per-position SGEMM -------------------
template <int O, int K, int NPOS, int HWIN, int WIN, int WOD, int STR,
          bool RELU>
__global__ __launch_bounds__(256) void k_lcg(const float* __restrict__ X,
                                             const float* __restrict__ Wt,
                                             const float* __restrict__ bias,
                                             float* __restrict__ out, int B) {
  constexpr int KT = 16;
  constexpr int TO = O / 4;
  constexpr int TB = 256 / TO;
  constexpr int BPT = 128 / TB;
  constexpr int NSTEP = K / KT;
  constexpr int WF4 = KT * O / 4;
  __shared__ float Xs[2][KT][128];
  __shared__ float Ws[2][KT][O];
  __shared__ int rowtab[K];
  const int tid = threadIdx.x;
  const int b0 = blockIdx.x * 128;
  const int pos = blockIdx.y;
  const int ho = pos / WOD, wo = pos - ho * WOD;

  for (int k = tid; k < K; k += 256) {
    const int c = k / 9, kk = k - c * 9;
    const int kh = kk / 3, kw = kk - kh * 3;
    rowtab[k] = c * HWIN + (ho * STR + kh) * WIN + (wo * STR + kw);
  }
  __syncthreads();

  const float* wsrc = Wt + (size_t)pos * K * O;
  const int xr0 = tid >> 5, xq0 = (tid & 31) * 4;
  const int xr1 = (tid + 256) >> 5, xq1 = ((tid + 256) & 31) * 4;
  const int wr = tid / (O / 4), wc = (tid % (O / 4)) * 4;
  const int to = tid % TO, tb = tid / TO;

  float4 xv0, xv1, wv0;
  xv0 = *(const float4*)&X[(size_t)rowtab[xr0] * B + b0 + xq0];
  xv1 = *(const float4*)&X[(size_t)rowtab[xr1] * B + b0 + xq1];
  if (WF4 == 256 || tid < WF4) wv0 = *(const float4*)&wsrc[tid * 4];

  float acc[4][BPT];
#pragma unroll
  for (int oo = 0; oo < 4; ++oo)
#pragma unroll
    for (int bb = 0; bb < BPT; ++bb) acc[oo][bb] = 0.f;

  *(float4*)&Xs[0][xr0][xq0] = xv0;
  *(float4*)&Xs[0][xr1][xq1] = xv1;
  if (WF4 == 256 || tid < WF4) *(float4*)&Ws[0][wr][wc] = wv0;
  __syncthreads();

  for (int t = 0; t < NSTEP; ++t) {
    const int cur = t & 1;
    if (t < NSTEP - 1) {
      const int k0 = (t + 1) * KT;
      xv0 = *(const float4*)&X[(size_t)rowtab[k0 + xr0] * B + b0 + xq0];
      xv1 = *(const float4*)&X[(size_t)rowtab[k0 + xr1] * B + b0 + xq1];
      if (WF4 == 256 || tid < WF4)
        wv0 = *(const float4*)&wsrc[(size_t)k0 * O + tid * 4];
    }
#pragma unroll
    for (int k = 0; k < KT; ++k) {
      const float4 w4 = *(const float4*)&Ws[cur][k][to * 4];
#pragma unroll
      for (int q = 0; q < BPT / 4; ++q) {
        const float4 x4 = *(const float4*)&Xs[cur][k][tb * BPT + q * 4];
        const float xs[4] = {x4.x, x4.y, x4.z, x4.w};
        const float ws4[4] = {w4.x, w4.y, w4.z, w4.w};
#pragma unroll
        for (int oo = 0; oo < 4; ++oo)
#pragma unroll
          for (int j = 0; j < 4; ++j)
            acc[oo][q * 4 + j] = fmaf(ws4[oo], xs[j], acc[oo][q * 4 + j]);
      }
    }
    if (t < NSTEP - 1) {
      const int nxt = cur ^ 1;
      *(float4*)&Xs[nxt][xr0][xq0] = xv0;
      *(float4*)&Xs[nxt][xr1][xq1] = xv1;
      if (WF4 == 256 || tid < WF4) *(float4*)&Ws[nxt][wr][wc] = wv0;
    }
    __syncthreads();
  }

#pragma unroll
  for (int oo = 0; oo < 4; ++oo) {
    const int f = (to * 4 + oo) * NPOS + pos;
    const float bz = bias[f];
#pragma unroll
    for (int q = 0; q < BPT / 4; ++q) {
      float4 r;
      r.x = acc[oo][q * 4 + 0] + bz;
      r.y = acc[oo][q * 4 + 1] + bz;
      r.z = acc[oo][q * 4 + 2] + bz;
      r.w = acc[oo][q * 4 + 3] + bz;
      if (RELU) {
        r.x = fmaxf(r.x, 0.f);
        r.y = fmaxf(r.y, 0.f);
        r.z = fmaxf(r.z, 0.f);
        r.w = fmaxf(r.w, 0.f);
      }
      *(float4*)&out[(size_t)f * B + b0 + tb * BPT + q * 4] = r;
    }
  }
}

// ---------------- FC1 via bf16 MFMA ----------------------------------------
// h4[512,B] = relu(fw1[512,1024] @ h3[1024,B] + fb1), fp32 accumulate.
// Block: 128j x 128b, 4 waves (wave = 32j x 128b = 2x8 16x16 tiles), KT=32.
// Wl rows: [j][32k] bf16, 80B padded rows. Xl rows: [b][32k] bf16, 80B rows
// + MONOTONE stagger (b>>3)*16B (R8 fix: the &7-wrapped stagger overlapped
// rows 56-63 with 64-71; monotone stagger can never overlap).
__global__ __launch_bounds__(256) void k_fc1m(const float* __restrict__ X,
                                              const unsigned short* __restrict__ Wbf,
                                              const float* __restrict__ fb1,
                                              float* __restrict__ out, int B) {
  __shared__ short Wl[2][5120];   // 128 rows x 40 shorts
  __shared__ short Xl[2][5232];   // 128 rows x 40 + monotone stagger
  const int tid = threadIdx.x;
  const int b0 = blockIdx.x * 128, j0 = blockIdx.y * 128;
  const int w = tid >> 6, l = tid & 63, m = l & 15, g = l >> 4;

  // W staging: thread -> j=tid>>1, k-half kh=(tid&1)*16 (bf16 direct copy)
  const int wj = tid >> 1, wkh = (tid & 1) * 16;
  const unsigned short* wsrc = Wbf + (size_t)(j0 + wj) * 1024 + wkh;
  // X staging: thread -> k-pair kp=tid>>4, b-oct boct=(tid&15)*8
  const int kp = tid >> 4, boct = (tid & 15) * 8;
  const float* xsrc = X + (size_t)(2 * kp) * B + b0 + boct;

  f32x4 acc[2][8];
#pragma unroll
  for (int jt = 0; jt < 2; ++jt)
#pragma unroll
    for (int bt = 0; bt < 8; ++bt) acc[jt][bt] = (f32x4){0.f, 0.f, 0.f, 0.f};

  short8v wreg0, wreg1;
  float4 xreg[4];

  // ---- load t=0
  wreg0 = *(const short8v*)(wsrc);
  wreg1 = *(const short8v*)(wsrc + 8);
  xreg[0] = *(const float4*)(xsrc);
  xreg[1] = *(const float4*)(xsrc + 4);
  xreg[2] = *(const float4*)(xsrc + B);
  xreg[3] = *(const float4*)(xsrc + B + 4);

  // ---- write buf 0
  {
    *(short8v*)&Wl[0][wj * 40 + wkh] = wreg0;
    *(short8v*)&Wl[0][wj * 40 + wkh + 8] = wreg1;
    unsigned* xl = (unsigned*)&Xl[0][0];
    const float* x0 = (const float*)&xreg[0];
    const float* x1 = (const float*)&xreg[2];
#pragma unroll
    for (int i = 0; i < 8; ++i) {
      const int b = boct + i;
      const unsigned lo = f2bf(x0[i]), hi = f2bf(x1[i]);
      xl[b * 20 + (b >> 3) * 4 + kp] = lo | (hi << 16);
    }
  }
  __syncthreads();

  for (int t = 0; t < 32; ++t) {
    const int cur = t & 1;
    if (t < 31) {
      const unsigned short* wp = wsrc + (t + 1) * 32;
      wreg0 = *(const short8v*)(wp);
      wreg1 = *(const short8v*)(wp + 8);
      const float* xp = xsrc + (size_t)(t + 1) * 32 * B;
      xreg[0] = *(const float4*)(xp);
      xreg[1] = *(const float4*)(xp + 4);
      xreg[2] = *(const float4*)(xp + B);
      xreg[3] = *(const float4*)(xp + B + 4);
    }
    // ---- fragments + MFMA
    {
      short8v aw[2], bx[8];
#pragma unroll
      for (int jt = 0; jt < 2; ++jt)
        aw[jt] = *(const short8v*)&Wl[cur][(w * 32 + jt * 16 + m) * 40 + g * 8];
#pragma unroll
      for (int bt = 0; bt < 8; ++bt) {
        const int b = bt * 16 + m;
        bx[bt] = *(const short8v*)&Xl[cur][b * 40 + (b >> 3) * 8 + g * 8];
      }
#pragma unroll
      for (int jt = 0; jt < 2; ++jt)
#pragma unroll
        for (int bt = 0; bt < 8; ++bt)
          acc[jt][bt] = __builtin_amdgcn_mfma_f32_16x16x32_bf16(
              aw[jt], bx[bt], acc[jt][bt], 0, 0, 0);
    }
    if (t < 31) {
      const int nxt = cur ^ 1;
      *(short8v*)&Wl[nxt][wj * 40 + wkh] = wreg0;
      *(short8v*)&Wl[nxt][wj * 40 + wkh + 8] = wreg1;
      unsigned* xl = (unsigned*)&Xl[nxt][0];
      const float* x0 = (const float*)&xreg[0];
      const float* x1 = (const float*)&xreg[2];
#pragma unroll
      for (int i = 0; i < 8; ++i) {
        const int b = boct + i;
        const unsigned lo = f2bf(x0[i]), hi = f2bf(x1[i]);
        xl[b * 20 + (b >> 3) * 4 + kp] = lo | (hi << 16);
      }
    }
    __syncthreads();
  }

  // ---- epilogue: bias + relu; D layout: col=lane&15 (b), row=(l>>4)*4+r (j)
#pragma unroll
  for (int jt = 0; jt < 2; ++jt)
#pragma unroll
    for (int r = 0; r < 4; ++r) {
      const int j = j0 + w * 32 + jt * 16 + g * 4 + r;
      const float bj = fb1[j];
#pragma unroll
      for (int bt = 0; bt < 8; ++bt)
        out[(size_t)j * B + b0 + bt * 16 + m] =
            fmaxf(acc[jt][bt][r] + bj, 0.f);
    }
}

// ---------------- FC2: out[b,10] = fw2[10,512] @ h4[512,B] + fb2 -----------
__global__ __launch_bounds__(256) void k_fc2(const float* __restrict__ in,
                                             const float* __restrict__ fw2,
                                             const float* __restrict__ fb2,
                                             float* __restrict__ out, int B,
                                             int b0) {
  __shared__ float red[4][10][64];
  const int tx = threadIdx.x;
  const int b = blockIdx.x * 64 + tx;
  const int tyu = threadIdx.y;
  float acc[10];
#pragma unroll
  for (int i = 0; i < 10; ++i) acc[i] = 0.f;
  for (int kk = 0; kk < 128; ++kk) {
    const int k = tyu * 128 + kk;
    const float v = in[(size_t)k * B + b];
#pragma unroll
    for (int i = 0; i < 10; ++i) acc[i] = fmaf(v, fw2[i * 512 + k], acc[i]);
  }
#pragma unroll
  for (int i = 0; i < 10; ++i) red[tyu][i][tx] = acc[i];
  __syncthreads();
  if (threadIdx.y == 0) {
#pragma unroll
    for (int i = 0; i < 10; ++i) {
      const float s = fb2[i] + red[0][i][tx] + red[1][i][tx] + red[2][i][tx] +
                      red[3][i][tx];
      out[(size_t)(b0 + b) * 10 + i] = s;
    }
  }
}

extern "C" void kernel_launch(void* const* d_in, const int* in_sizes, int n_in,
                              void* d_out, int out_size, void* d_ws,
                              size_t ws_size, hipStream_t stream) {
  const float* x   = (const float*)d_in[0];
  const float* w1  = (const float*)d_in[1];
  const float* b1  = (const float*)d_in[2];
  const float* w2  = (const float*)d_in[3];
  const float* b2  = (const float*)d_in[4];
  const float* w3  = (const float*)d_in[5];
  const float* b3  = (const float*)d_in[6];
  const float* fw1 = (const float*)d_in[7];
  const float* fb1 = (const float*)d_in[8];
  const float* fw2 = (const float*)d_in[9];
  const float* fb2 = (const float*)d_in[10];
  float* out = (float*)d_out;

  const int B = in_sizes[0] / 784;  // 8192

  // ws: Wt2 | Wt3 | Wbf(512x1024 bf16) | per-chunk buffers
  const size_t nWt2 = (size_t)36 * 144 * 32;   // 165888
  const size_t nWt3 = (size_t)16 * 288 * 64;   // 294912
  const size_t nWbf = (size_t)512 * 1024 / 2;  // bf16 as float-count: 262144
  float* Wt2 = (float*)d_ws;
  float* Wt3 = Wt2 + nWt2;
  unsigned short* Wbf = (unsigned short*)(Wt3 + nWt3);
  float* base = Wt3 + nWt3 + nWbf;
  const size_t ws_rem = ws_size - (nWt2 + nWt3 + nWbf) * sizeof(float);

  const size_t per_elem = (size_t)(784 + 2704 + 1152) * sizeof(float);
  int Bc = B;
  while ((size_t)Bc * per_elem > ws_rem && Bc > 512) Bc >>= 1;
  const int nch = B / Bc;

  float* P0 = base;                      // xT[784,Bc] then h4[512,Bc]
  float* P1 = P0 + (size_t)784 * Bc;     // h1[2704,Bc] then h3[1024,Bc]
  float* P2 = P1 + (size_t)2704 * Bc;    // h2[1152,Bc]

  // one-time weight transforms
  k_wt<32, 16, 36><<<dim3(36, 36), dim3(32, 4), 0, stream>>>(w2, Wt2);
  k_wt<64, 32, 16><<<dim3(16, 72), dim3(64, 4), 0, stream>>>(w3, Wt3);
  k_wbf<<<dim3(256), 256, 0, stream>>>(fw1, Wbf);

  for (int ch = 0; ch < nch; ++ch) {
    const float* xc = x + (size_t)ch * Bc * 784;
    const int b0 = ch * Bc;
    const int nb = Bc / 64;

    k_tr<<<dim3(Bc / 32, 25), dim3(32, 8), 0, stream>>>(xc, P0, Bc);
    k_lc1<<<dim3(nb, 13), dim3(64, 4), 0, stream>>>(P0, w1, b1, P1, Bc);
    k_lcg<32, 144, 36, 169, 13, 6, 2, true>
        <<<dim3(Bc / 128, 36), dim3(256), 0, stream>>>(P1, Wt2, b2, P2, Bc);
    k_lcg<64, 288, 16, 36, 6, 4, 1, false>
        <<<dim3(Bc / 128, 16), dim3(256), 0, stream>>>(P2, Wt3, b3, P1, Bc);
    k_fc1m<<<dim3(Bc / 128, 4), 256, 0, stream>>>(P1, Wbf, fb1, P0, Bc);
    k_fc2<<<dim3(nb), dim3(64, 4), 0, stream>>>(P0, fw2, fb2, out, Bc, b0);
  }
}

// Round 10
// 158.621 us; speedup vs baseline: 5.7956x; 1.3940x over previous
//
#include <hip/hip_runtime.h>

typedef __attribute__((ext_vector_type(8))) short short8v;   // 8 bf16
typedef __attribute__((ext_vector_type(4))) float f32x4;

static __device__ __forceinline__ unsigned short f2bf(float f) {
  union { float f; unsigned u; } v;
  v.f = f;
  const unsigned u = v.u;
  return (unsigned short)((u + 0x7FFF + ((u >> 16) & 1)) >> 16);  // RNE
}

// Activations in batch-last layout [feature, B]; lanes = batch (coalesced).

// ---------------- transpose x[B,784] -> xT[784, Bc] ----------------
__global__ __launch_bounds__(256) void k_tr(const float* __restrict__ x,
                                            float* __restrict__ xT, int Bc) {
  __shared__ float t[32][33];
  const int b0 = blockIdx.x * 32;
  const int f0 = blockIdx.y * 32;
  const int tx = threadIdx.x, ty = threadIdx.y;
  for (int r = ty; r < 32; r += 8) {
    const int f = f0 + tx;
    t[r][tx] = (f < 784) ? x[(size_t)(b0 + r) * 784 + f] : 0.f;
  }
  __syncthreads();
  for (int r = ty; r < 32; r += 8) {
    const int f = f0 + r;
    if (f < 784) xT[(size_t)f * Bc + b0 + tx] = t[tx][r];
  }
}

// ---------------- LC1: [1,28,28] -> [16,13,13], stride 2, relu -------------
__global__ __launch_bounds__(256) void k_lc1(const float* __restrict__ in,
                                             const float* __restrict__ w,
                                             const float* __restrict__ bias,
                                             float* __restrict__ out, int B) {
  const int b = blockIdx.x * 64 + threadIdx.x;
  const int ho = blockIdx.y;
  const int o0 = threadIdx.y * 4;
  float xv[3][27];
#pragma unroll
  for (int r = 0; r < 3; ++r)
#pragma unroll
    for (int col = 0; col < 27; ++col)
      xv[r][col] = in[(size_t)((2 * ho + r) * 28 + col) * B + b];
  float acc[4][13];
#pragma unroll
  for (int oo = 0; oo < 4; ++oo)
#pragma unroll
    for (int wo = 0; wo < 13; ++wo)
      acc[oo][wo] = bias[(o0 + oo) * 169 + ho * 13 + wo];
#pragma unroll
  for (int oo = 0; oo < 4; ++oo)
#pragma unroll
    for (int wo = 0; wo < 13; ++wo) {
      const float* wp = w + (size_t)((o0 + oo) * 169 + ho * 13 + wo) * 9;
#pragma unroll
      for (int kh = 0; kh < 3; ++kh)
#pragma unroll
        for (int kw = 0; kw < 3; ++kw)
          acc[oo][wo] = fmaf(xv[kh][2 * wo + kw], wp[kh * 3 + kw], acc[oo][wo]);
    }
#pragma unroll
  for (int oo = 0; oo < 4; ++oo)
#pragma unroll
    for (int wo = 0; wo < 13; ++wo)
      out[(size_t)((o0 + oo) * 169 + ho * 13 + wo) * B + b] =
          fmaxf(acc[oo][wo], 0.f);
}

// ------ LC weight -> bf16 [pos][o][Kpad], zero-padded k >= K ---------------
template <int O, int C, int NPOS, int Kpad>
__global__ void k_wmc(const float* __restrict__ w,
                      unsigned short* __restrict__ wm) {
  const int pos = blockIdx.x, o = blockIdx.y, k = threadIdx.x;
  float v = 0.f;
  if (k < C * 9) {
    const int c = k / 9, kk = k - c * 9;
    v = w[((size_t)(o * C + c) * NPOS + pos) * 9 + kk];
  }
  wm[((size_t)pos * O + o) * Kpad + k] = f2bf(v);
}

// ---------------- fw1 -> bf16 copy (once) ----------------------------------
__global__ __launch_bounds__(256) void k_wbf(const float* __restrict__ w,
                                             unsigned short* __restrict__ o) {
  const int i = (blockIdx.x * 256 + threadIdx.x) * 8;
  const float4 a = *(const float4*)&w[i];
  const float4 b = *(const float4*)&w[i + 4];
  short8v r;
  r[0] = (short)f2bf(a.x); r[1] = (short)f2bf(a.y);
  r[2] = (short)f2bf(a.z); r[3] = (short)f2bf(a.w);
  r[4] = (short)f2bf(b.x); r[5] = (short)f2bf(b.y);
  r[6] = (short)f2bf(b.z); r[7] = (short)f2bf(b.w);
  *(short8v*)&o[i] = r;
}

// ---------------- LC layer via bf16 MFMA (fc1m skeleton) -------------------
// One block = one position x 128-batch tile. KT=32 double-buffered; X rows
// gathered via rowtab (pad rows -> row 0, pad values zeroed); W from bf16
// Wm[pos][o][Kpad] (zero-padded). Monotone-stagger Xl (R8-proven).
template <int O, int K, int NPOS, int HWIN, int WIN, int WOD, int STR,
          bool RELU>
__global__ __launch_bounds__(256) void k_lcm(
    const float* __restrict__ X, const unsigned short* __restrict__ Wm,
    const float* __restrict__ bias, float* __restrict__ out, int B) {
  constexpr int NSTEP = (K + 31) / 32;
  constexpr int Kpad = NSTEP * 32;
  constexpr int NBT = (O == 64) ? 8 : 4;  // b-tiles per wave
  __shared__ short Wl[2][O * 40];
  __shared__ short Xl[2][5232];
  __shared__ int rowtab[Kpad];
  const int tid = threadIdx.x;
  const int b0 = blockIdx.x * 128;
  const int pos = blockIdx.y;
  const int ho = pos / WOD, wo = pos - ho * WOD;
  const int w = tid >> 6, l = tid & 63, m = l & 15, g = l >> 4;
  const int jw = (O == 64) ? w * 16 : (w & 1) * 16;
  const int boff = (O == 64) ? 0 : (w >> 1) * 64;

  for (int k = tid; k < Kpad; k += 256) {
    int r = 0;
    if (k < K) {
      const int c = k / 9, kk = k - c * 9;
      const int kh = kk / 3, kw = kk - kh * 3;
      r = c * HWIN + (ho * STR + kh) * WIN + (wo * STR + kw);
    }
    rowtab[k] = r;
  }
  __syncthreads();

  const unsigned short* wsrc = Wm + (size_t)pos * O * Kpad;
  const int wjj = tid >> 2, wko = (tid & 3) * 8;
  const bool wact = tid < O * 4;
  const int kp = tid >> 4, boct = (tid & 15) * 8;

  f32x4 acc[NBT];
#pragma unroll
  for (int bt = 0; bt < NBT; ++bt) acc[bt] = (f32x4){0.f, 0.f, 0.f, 0.f};

  short8v wreg;
  float4 xr[4];
  bool z0, z1;

  // ---- load chunk 0
  if (wact) wreg = *(const short8v*)&wsrc[(size_t)wjj * Kpad + wko];
  {
    const int k0 = 2 * kp;
    z0 = k0 >= K;
    z1 = k0 + 1 >= K;
    const float* p0 = X + (size_t)rowtab[k0] * B + b0 + boct;
    const float* p1 = X + (size_t)rowtab[k0 + 1] * B + b0 + boct;
    xr[0] = *(const float4*)p0;
    xr[1] = *(const float4*)(p0 + 4);
    xr[2] = *(const float4*)p1;
    xr[3] = *(const float4*)(p1 + 4);
  }
  // ---- write buf 0
  if (wact) *(short8v*)&Wl[0][wjj * 40 + wko] = wreg;
  {
    unsigned* xl = (unsigned*)&Xl[0][0];
    const float* x0 = (const float*)&xr[0];
    const float* x1 = (const float*)&xr[2];
#pragma unroll
    for (int i = 0; i < 8; ++i) {
      const int b = boct + i;
      const unsigned lo = z0 ? 0u : (unsigned)f2bf(x0[i]);
      const unsigned hi = z1 ? 0u : (unsigned)f2bf(x1[i]);
      xl[b * 20 + (b >> 3) * 4 + kp] = lo | (hi << 16);
    }
  }
  __syncthreads();

  for (int t = 0; t < NSTEP; ++t) {
    const int cur = t & 1;
    if (t < NSTEP - 1) {
      const int kc = (t + 1) * 32;
      if (wact) wreg = *(const short8v*)&wsrc[(size_t)wjj * Kpad + kc + wko];
      const int k0 = kc + 2 * kp;
      z0 = k0 >= K;
      z1 = k0 + 1 >= K;
      const float* p0 = X + (size_t)rowtab[k0] * B + b0 + boct;
      const float* p1 = X + (size_t)rowtab[k0 + 1] * B + b0 + boct;
      xr[0] = *(const float4*)p0;
      xr[1] = *(const float4*)(p0 + 4);
      xr[2] = *(const float4*)p1;
      xr[3] = *(const float4*)(p1 + 4);
    }
    {
      const short8v aw = *(const short8v*)&Wl[cur][(jw + m) * 40 + g * 8];
      short8v bx[NBT];
#pragma unroll
      for (int bt = 0; bt < NBT; ++bt) {
        const int b = boff + bt * 16 + m;
        bx[bt] = *(const short8v*)&Xl[cur][b * 40 + (b >> 3) * 8 + g * 8];
      }
#pragma unroll
      for (int bt = 0; bt < NBT; ++bt)
        acc[bt] = __builtin_amdgcn_mfma_f32_16x16x32_bf16(aw, bx[bt], acc[bt],
                                                          0, 0, 0);
    }
    if (t < NSTEP - 1) {
      const int nxt = cur ^ 1;
      if (wact) *(short8v*)&Wl[nxt][wjj * 40 + wko] = wreg;
      unsigned* xl = (unsigned*)&Xl[nxt][0];
      const float* x0 = (const float*)&xr[0];
      const float* x1 = (const float*)&xr[2];
#pragma unroll
      for (int i = 0; i < 8; ++i) {
        const int b = boct + i;
        const unsigned lo = z0 ? 0u : (unsigned)f2bf(x0[i]);
        const unsigned hi = z1 ? 0u : (unsigned)f2bf(x1[i]);
        xl[b * 20 + (b >> 3) * 4 + kp] = lo | (hi << 16);
      }
    }
    __syncthreads();
  }

  // ---- epilogue: D col=lane&15 (b), row=g*4+r (o); f = o*NPOS + pos
#pragma unroll
  for (int r = 0; r < 4; ++r) {
    const int o = jw + g * 4 + r;
    const int f = o * NPOS + pos;
    const float bz = bias[f];
#pragma unroll
    for (int bt = 0; bt < NBT; ++bt) {
      float v = acc[bt][r] + bz;
      if (RELU) v = fmaxf(v, 0.f);
      out[(size_t)f * B + b0 + boff + bt * 16 + m] = v;
    }
  }
}

// ---------------- FC1 via bf16 MFMA ----------------------------------------
__global__ __launch_bounds__(256) void k_fc1m(const float* __restrict__ X,
                                              const unsigned short* __restrict__ Wbf,
                                              const float* __restrict__ fb1,
                                              float* __restrict__ out, int B) {
  __shared__ short Wl[2][5120];   // 128 rows x 40 shorts
  __shared__ short Xl[2][5232];   // 128 rows x 40 + monotone stagger
  const int tid = threadIdx.x;
  const int b0 = blockIdx.x * 128, j0 = blockIdx.y * 128;
  const int w = tid >> 6, l = tid & 63, m = l & 15, g = l >> 4;

  const int wj = tid >> 1, wkh = (tid & 1) * 16;
  const unsigned short* wsrc = Wbf + (size_t)(j0 + wj) * 1024 + wkh;
  const int kp = tid >> 4, boct = (tid & 15) * 8;
  const float* xsrc = X + (size_t)(2 * kp) * B + b0 + boct;

  f32x4 acc[2][8];
#pragma unroll
  for (int jt = 0; jt < 2; ++jt)
#pragma unroll
    for (int bt = 0; bt < 8; ++bt) acc[jt][bt] = (f32x4){0.f, 0.f, 0.f, 0.f};

  short8v wreg0, wreg1;
  float4 xreg[4];

  wreg0 = *(const short8v*)(wsrc);
  wreg1 = *(const short8v*)(wsrc + 8);
  xreg[0] = *(const float4*)(xsrc);
  xreg[1] = *(const float4*)(xsrc + 4);
  xreg[2] = *(const float4*)(xsrc + B);
  xreg[3] = *(const float4*)(xsrc + B + 4);

  {
    *(short8v*)&Wl[0][wj * 40 + wkh] = wreg0;
    *(short8v*)&Wl[0][wj * 40 + wkh + 8] = wreg1;
    unsigned* xl = (unsigned*)&Xl[0][0];
    const float* x0 = (const float*)&xreg[0];
    const float* x1 = (const float*)&xreg[2];
#pragma unroll
    for (int i = 0; i < 8; ++i) {
      const int b = boct + i;
      const unsigned lo = f2bf(x0[i]), hi = f2bf(x1[i]);
      xl[b * 20 + (b >> 3) * 4 + kp] = lo | (hi << 16);
    }
  }
  __syncthreads();

  for (int t = 0; t < 32; ++t) {
    const int cur = t & 1;
    if (t < 31) {
      const unsigned short* wp = wsrc + (t + 1) * 32;
      wreg0 = *(const short8v*)(wp);
      wreg1 = *(const short8v*)(wp + 8);
      const float* xp = xsrc + (size_t)(t + 1) * 32 * B;
      xreg[0] = *(const float4*)(xp);
      xreg[1] = *(const float4*)(xp + 4);
      xreg[2] = *(const float4*)(xp + B);
      xreg[3] = *(const float4*)(xp + B + 4);
    }
    {
      short8v aw[2], bx[8];
#pragma unroll
      for (int jt = 0; jt < 2; ++jt)
        aw[jt] = *(const short8v*)&Wl[cur][(w * 32 + jt * 16 + m) * 40 + g * 8];
#pragma unroll
      for (int bt = 0; bt < 8; ++bt) {
        const int b = bt * 16 + m;
        bx[bt] = *(const short8v*)&Xl[cur][b * 40 + (b >> 3) * 8 + g * 8];
      }
#pragma unroll
      for (int jt = 0; jt < 2; ++jt)
#pragma unroll
        for (int bt = 0; bt < 8; ++bt)
          acc[jt][bt] = __builtin_amdgcn_mfma_f32_16x16x32_bf16(
              aw[jt], bx[bt], acc[jt][bt], 0, 0, 0);
    }
    if (t < 31) {
      const int nxt = cur ^ 1;
      *(short8v*)&Wl[nxt][wj * 40 + wkh] = wreg0;
      *(short8v*)&Wl[nxt][wj * 40 + wkh + 8] = wreg1;
      unsigned* xl = (unsigned*)&Xl[nxt][0];
      const float* x0 = (const float*)&xreg[0];
      const float* x1 = (const float*)&xreg[2];
#pragma unroll
      for (int i = 0; i < 8; ++i) {
        const int b = boct + i;
        const unsigned lo = f2bf(x0[i]), hi = f2bf(x1[i]);
        xl[b * 20 + (b >> 3) * 4 + kp] = lo | (hi << 16);
      }
    }
    __syncthreads();
  }

#pragma unroll
  for (int jt = 0; jt < 2; ++jt)
#pragma unroll
    for (int r = 0; r < 4; ++r) {
      const int j = j0 + w * 32 + jt * 16 + g * 4 + r;
      const float bj = fb1[j];
#pragma unroll
      for (int bt = 0; bt < 8; ++bt)
        out[(size_t)j * B + b0 + bt * 16 + m] =
            fmaxf(acc[jt][bt][r] + bj, 0.f);
    }
}

// ---------------- FC2: out[b,10] = fw2[10,512] @ h4[512,B] + fb2 -----------
__global__ __launch_bounds__(256) void k_fc2(const float* __restrict__ in,
                                             const float* __restrict__ fw2,
                                             const float* __restrict__ fb2,
                                             float* __restrict__ out, int B,
                                             int b0) {
  __shared__ float red[4][10][64];
  const int tx = threadIdx.x;
  const int b = blockIdx.x * 64 + tx;
  const int tyu = threadIdx.y;
  float acc[10];
#pragma unroll
  for (int i = 0; i < 10; ++i) acc[i] = 0.f;
  for (int kk = 0; kk < 128; ++kk) {
    const int k = tyu * 128 + kk;
    const float v = in[(size_t)k * B + b];
#pragma unroll
    for (int i = 0; i < 10; ++i) acc[i] = fmaf(v, fw2[i * 512 + k], acc[i]);
  }
#pragma unroll
  for (int i = 0; i < 10; ++i) red[tyu][i][tx] = acc[i];
  __syncthreads();
  if (threadIdx.y == 0) {
#pragma unroll
    for (int i = 0; i < 10; ++i) {
      const float s = fb2[i] + red[0][i][tx] + red[1][i][tx] + red[2][i][tx] +
                      red[3][i][tx];
      out[(size_t)(b0 + b) * 10 + i] = s;
    }
  }
}

extern "C" void kernel_launch(void* const* d_in, const int* in_sizes, int n_in,
                              void* d_out, int out_size, void* d_ws,
                              size_t ws_size, hipStream_t stream) {
  const float* x   = (const float*)d_in[0];
  const float* w1  = (const float*)d_in[1];
  const float* b1  = (const float*)d_in[2];
  const float* w2  = (const float*)d_in[3];
  const float* b2  = (const float*)d_in[4];
  const float* w3  = (const float*)d_in[5];
  const float* b3  = (const float*)d_in[6];
  const float* fw1 = (const float*)d_in[7];
  const float* fb1 = (const float*)d_in[8];
  const float* fw2 = (const float*)d_in[9];
  const float* fb2 = (const float*)d_in[10];
  float* out = (float*)d_out;

  const int B = in_sizes[0] / 784;  // 8192

  // ws: Wm2[36*32*160 bf16] | Wm3[16*64*288 bf16] | Wbf[512*1024 bf16] | bufs
  const size_t nWm2 = (size_t)36 * 32 * 160 / 2;   // 92160 float-equiv
  const size_t nWm3 = (size_t)16 * 64 * 288 / 2;   // 147456
  const size_t nWbf = (size_t)512 * 1024 / 2;      // 262144
  unsigned short* Wm2 = (unsigned short*)d_ws;
  unsigned short* Wm3 = (unsigned short*)((float*)d_ws + nWm2);
  unsigned short* Wbf = (unsigned short*)((float*)d_ws + nWm2 + nWm3);
  float* base = (float*)d_ws + nWm2 + nWm3 + nWbf;
  const size_t ws_rem = ws_size - (nWm2 + nWm3 + nWbf) * sizeof(float);

  const size_t per_elem = (size_t)(784 + 2704 + 1152) * sizeof(float);
  int Bc = B;
  while ((size_t)Bc * per_elem > ws_rem && Bc > 512) Bc >>= 1;
  const int nch = B / Bc;

  float* P0 = base;                      // xT[784,Bc] then h4[512,Bc]
  float* P1 = P0 + (size_t)784 * Bc;     // h1[2704,Bc] then h3[1024,Bc]
  float* P2 = P1 + (size_t)2704 * Bc;    // h2[1152,Bc]

  // one-time weight transforms
  k_wmc<32, 16, 36, 160><<<dim3(36, 32), 160, 0, stream>>>(w2, Wm2);
  k_wmc<64, 32, 16, 288><<<dim3(16, 64), 288, 0, stream>>>(w3, Wm3);
  k_wbf<<<dim3(256), 256, 0, stream>>>(fw1, Wbf);

  for (int ch = 0; ch < nch; ++ch) {
    const float* xc = x + (size_t)ch * Bc * 784;
    const int b0 = ch * Bc;
    const int nb = Bc / 64;

    k_tr<<<dim3(Bc / 32, 25), dim3(32, 8), 0, stream>>>(xc, P0, Bc);
    k_lc1<<<dim3(nb, 13), dim3(64, 4), 0, stream>>>(P0, w1, b1, P1, Bc);
    // LC2: h1[2704,Bc] (C=16,13x13) -> h2[1152,Bc]; 36 positions
    k_lcm<32, 144, 36, 169, 13, 6, 2, true>
        <<<dim3(Bc / 128, 36), 256, 0, stream>>>(P1, Wm2, b2, P2, Bc);
    // LC3: h2[1152,Bc] (C=32,6x6) -> h3[1024,Bc]; 16 positions
    k_lcm<64, 288, 16, 36, 6, 4, 1, false>
        <<<dim3(Bc / 128, 16), 256, 0, stream>>>(P2, Wm3, b3, P1, Bc);
    k_fc1m<<<dim3(Bc / 128, 4), 256, 0, stream>>>(P1, Wbf, fb1, P0, Bc);
    k_fc2<<<dim3(nb), dim3(64, 4), 0, stream>>>(P0, fw2, fb2, out, Bc, b0);
  }
}

// Round 11
// 137.354 us; speedup vs baseline: 6.6930x; 1.1548x over previous
//
#include <hip/hip_runtime.h>

typedef __attribute__((ext_vector_type(8))) short short8v;   // 8 bf16
typedef __attribute__((ext_vector_type(4))) float f32x4;

static __device__ __forceinline__ unsigned short f2bf(float f) {
  union { float f; unsigned u; } v;
  v.f = f;
  const unsigned u = v.u;
  return (unsigned short)((u + 0x7FFF + ((u >> 16) & 1)) >> 16);  // RNE
}
static __device__ __forceinline__ float bf2f(unsigned short s) {
  union { unsigned u; float f; } v;
  v.u = ((unsigned)s) << 16;
  return v.f;
}

// Intermediates h1..h4 stored bf16 in [feature, B] layout (batch-last).
// Producers round with RNE; consumers (MFMA kernels) previously rounded the
// same values during staging, so h1/h2/h3 consumers see identical bits.

// ------- LC1 fused with input transpose: x[B,784] f32 -> h1[2704,B] bf16 ---
// grid (B/64, 13=ho), block 256. Stage rows 2ho..2ho+2 (84 contiguous floats
// per batch) into LDS [64][89] (89: lane*89 mod 32 spans all banks -> 2-way).
__global__ __launch_bounds__(256) void k_lc1(const float* __restrict__ x,
                                             const float* __restrict__ w,
                                             const float* __restrict__ bias,
                                             unsigned short* __restrict__ out,
                                             int B) {
  __shared__ float Xs[64][89];
  const int tid = threadIdx.x;
  const int b0 = blockIdx.x * 64;
  const int ho = blockIdx.y;
  const int fbase = 2 * ho * 28;

  for (int idx = tid; idx < 1344; idx += 256) {  // 64 b x 21 float4
    const int b = idx / 21, q = idx - b * 21;
    const float4 v =
        *(const float4*)&x[(size_t)(b0 + b) * 784 + fbase + q * 4];
    Xs[b][q * 4 + 0] = v.x;
    Xs[b][q * 4 + 1] = v.y;
    Xs[b][q * 4 + 2] = v.z;
    Xs[b][q * 4 + 3] = v.w;
  }
  __syncthreads();

  const int lane = tid & 63;
  const int o0 = (tid >> 6) * 4;
  float xv[3][27];
#pragma unroll
  for (int r = 0; r < 3; ++r)
#pragma unroll
    for (int col = 0; col < 27; ++col) xv[r][col] = Xs[lane][r * 28 + col];

  float acc[4][13];
#pragma unroll
  for (int oo = 0; oo < 4; ++oo)
#pragma unroll
    for (int wo = 0; wo < 13; ++wo)
      acc[oo][wo] = bias[(o0 + oo) * 169 + ho * 13 + wo];
#pragma unroll
  for (int oo = 0; oo < 4; ++oo)
#pragma unroll
    for (int wo = 0; wo < 13; ++wo) {
      const float* wp = w + (size_t)((o0 + oo) * 169 + ho * 13 + wo) * 9;
#pragma unroll
      for (int kh = 0; kh < 3; ++kh)
#pragma unroll
        for (int kw = 0; kw < 3; ++kw)
          acc[oo][wo] = fmaf(xv[kh][2 * wo + kw], wp[kh * 3 + kw], acc[oo][wo]);
    }
#pragma unroll
  for (int oo = 0; oo < 4; ++oo)
#pragma unroll
    for (int wo = 0; wo < 13; ++wo)
      out[(size_t)((o0 + oo) * 169 + ho * 13 + wo) * B + b0 + lane] =
          f2bf(fmaxf(acc[oo][wo], 0.f));
}

// ------ LC weight -> bf16 [pos][o][Kpad], zero-padded k >= K ---------------
template <int O, int C, int NPOS, int Kpad>
__global__ void k_wmc(const float* __restrict__ w,
                      unsigned short* __restrict__ wm) {
  const int pos = blockIdx.x, o = blockIdx.y, k = threadIdx.x;
  float v = 0.f;
  if (k < C * 9) {
    const int c = k / 9, kk = k - c * 9;
    v = w[((size_t)(o * C + c) * NPOS + pos) * 9 + kk];
  }
  wm[((size_t)pos * O + o) * Kpad + k] = f2bf(v);
}

// ---------------- fw1 -> bf16 copy (once) ----------------------------------
__global__ __launch_bounds__(256) void k_wbf(const float* __restrict__ w,
                                             unsigned short* __restrict__ o) {
  const int i = (blockIdx.x * 256 + threadIdx.x) * 8;
  const float4 a = *(const float4*)&w[i];
  const float4 b = *(const float4*)&w[i + 4];
  short8v r;
  r[0] = (short)f2bf(a.x); r[1] = (short)f2bf(a.y);
  r[2] = (short)f2bf(a.z); r[3] = (short)f2bf(a.w);
  r[4] = (short)f2bf(b.x); r[5] = (short)f2bf(b.y);
  r[6] = (short)f2bf(b.z); r[7] = (short)f2bf(b.w);
  *(short8v*)&o[i] = r;
}

// ---------------- LC layer via bf16 MFMA (bf16 in, bf16 out) ---------------
template <int O, int K, int NPOS, int HWIN, int WIN, int WOD, int STR,
          bool RELU>
__global__ __launch_bounds__(256) void k_lcm(
    const unsigned short* __restrict__ X, const unsigned short* __restrict__ Wm,
    const float* __restrict__ bias, unsigned short* __restrict__ out, int B) {
  constexpr int NSTEP = (K + 31) / 32;
  constexpr int Kpad = NSTEP * 32;
  constexpr int NBT = (O == 64) ? 8 : 4;  // b-tiles per wave
  __shared__ short Wl[2][O * 40];
  __shared__ short Xl[2][5232];
  __shared__ int rowtab[Kpad];
  const int tid = threadIdx.x;
  const int b0 = blockIdx.x * 128;
  const int pos = blockIdx.y;
  const int ho = pos / WOD, wo = pos - ho * WOD;
  const int w = tid >> 6, l = tid & 63, m = l & 15, g = l >> 4;
  const int jw = (O == 64) ? w * 16 : (w & 1) * 16;
  const int boff = (O == 64) ? 0 : (w >> 1) * 64;

  for (int k = tid; k < Kpad; k += 256) {
    int r = 0;
    if (k < K) {
      const int c = k / 9, kk = k - c * 9;
      const int kh = kk / 3, kw = kk - kh * 3;
      r = c * HWIN + (ho * STR + kh) * WIN + (wo * STR + kw);
    }
    rowtab[k] = r;
  }
  __syncthreads();

  const unsigned short* wsrc = Wm + (size_t)pos * O * Kpad;
  const int wjj = tid >> 2, wko = (tid & 3) * 8;
  const bool wact = tid < O * 4;
  const int kp = tid >> 4, boct = (tid & 15) * 8;

  f32x4 acc[NBT];
#pragma unroll
  for (int bt = 0; bt < NBT; ++bt) acc[bt] = (f32x4){0.f, 0.f, 0.f, 0.f};

  short8v wreg, xa, xb;
  bool z0, z1;

  // ---- load chunk 0
  if (wact) wreg = *(const short8v*)&wsrc[(size_t)wjj * Kpad + wko];
  {
    const int k0 = 2 * kp;
    z0 = k0 >= K;
    z1 = k0 + 1 >= K;
    xa = *(const short8v*)(X + (size_t)rowtab[k0] * B + b0 + boct);
    xb = *(const short8v*)(X + (size_t)rowtab[k0 + 1] * B + b0 + boct);
  }
  // ---- write buf 0
  if (wact) *(short8v*)&Wl[0][wjj * 40 + wko] = wreg;
  {
    unsigned* xl = (unsigned*)&Xl[0][0];
#pragma unroll
    for (int i = 0; i < 8; ++i) {
      const int b = boct + i;
      const unsigned lo = z0 ? 0u : (unsigned)(unsigned short)xa[i];
      const unsigned hi = z1 ? 0u : (unsigned)(unsigned short)xb[i];
      xl[b * 20 + (b >> 3) * 4 + kp] = lo | (hi << 16);
    }
  }
  __syncthreads();

  for (int t = 0; t < NSTEP; ++t) {
    const int cur = t & 1;
    if (t < NSTEP - 1) {
      const int kc = (t + 1) * 32;
      if (wact) wreg = *(const short8v*)&wsrc[(size_t)wjj * Kpad + kc + wko];
      const int k0 = kc + 2 * kp;
      z0 = k0 >= K;
      z1 = k0 + 1 >= K;
      xa = *(const short8v*)(X + (size_t)rowtab[k0] * B + b0 + boct);
      xb = *(const short8v*)(X + (size_t)rowtab[k0 + 1] * B + b0 + boct);
    }
    {
      const short8v aw = *(const short8v*)&Wl[cur][(jw + m) * 40 + g * 8];
      short8v bx[NBT];
#pragma unroll
      for (int bt = 0; bt < NBT; ++bt) {
        const int b = boff + bt * 16 + m;
        bx[bt] = *(const short8v*)&Xl[cur][b * 40 + (b >> 3) * 8 + g * 8];
      }
#pragma unroll
      for (int bt = 0; bt < NBT; ++bt)
        acc[bt] = __builtin_amdgcn_mfma_f32_16x16x32_bf16(aw, bx[bt], acc[bt],
                                                          0, 0, 0);
    }
    if (t < NSTEP - 1) {
      const int nxt = cur ^ 1;
      if (wact) *(short8v*)&Wl[nxt][wjj * 40 + wko] = wreg;
      unsigned* xl = (unsigned*)&Xl[nxt][0];
#pragma unroll
      for (int i = 0; i < 8; ++i) {
        const int b = boct + i;
        const unsigned lo = z0 ? 0u : (unsigned)(unsigned short)xa[i];
        const unsigned hi = z1 ? 0u : (unsigned)(unsigned short)xb[i];
        xl[b * 20 + (b >> 3) * 4 + kp] = lo | (hi << 16);
      }
    }
    __syncthreads();
  }

  // ---- epilogue: D col=lane&15 (b), row=g*4+r (o); f = o*NPOS + pos
#pragma unroll
  for (int r = 0; r < 4; ++r) {
    const int o = jw + g * 4 + r;
    const int f = o * NPOS + pos;
    const float bz = bias[f];
#pragma unroll
    for (int bt = 0; bt < NBT; ++bt) {
      float v = acc[bt][r] + bz;
      if (RELU) v = fmaxf(v, 0.f);
      out[(size_t)f * B + b0 + boff + bt * 16 + m] = f2bf(v);
    }
  }
}

// ---------------- FC1 via bf16 MFMA (bf16 in, bf16 out) --------------------
__global__ __launch_bounds__(256) void k_fc1m(
    const unsigned short* __restrict__ X,
    const unsigned short* __restrict__ Wbf, const float* __restrict__ fb1,
    unsigned short* __restrict__ out, int B) {
  __shared__ short Wl[2][5120];   // 128 rows x 40 shorts
  __shared__ short Xl[2][5232];   // 128 rows x 40 + monotone stagger
  const int tid = threadIdx.x;
  const int b0 = blockIdx.x * 128, j0 = blockIdx.y * 128;
  const int w = tid >> 6, l = tid & 63, m = l & 15, g = l >> 4;

  const int wj = tid >> 1, wkh = (tid & 1) * 16;
  const unsigned short* wsrc = Wbf + (size_t)(j0 + wj) * 1024 + wkh;
  const int kp = tid >> 4, boct = (tid & 15) * 8;
  const unsigned short* xsrc = X + (size_t)(2 * kp) * B + b0 + boct;

  f32x4 acc[2][8];
#pragma unroll
  for (int jt = 0; jt < 2; ++jt)
#pragma unroll
    for (int bt = 0; bt < 8; ++bt) acc[jt][bt] = (f32x4){0.f, 0.f, 0.f, 0.f};

  short8v wreg0, wreg1, xa, xb;

  wreg0 = *(const short8v*)(wsrc);
  wreg1 = *(const short8v*)(wsrc + 8);
  xa = *(const short8v*)(xsrc);
  xb = *(const short8v*)(xsrc + B);

  {
    *(short8v*)&Wl[0][wj * 40 + wkh] = wreg0;
    *(short8v*)&Wl[0][wj * 40 + wkh + 8] = wreg1;
    unsigned* xl = (unsigned*)&Xl[0][0];
#pragma unroll
    for (int i = 0; i < 8; ++i) {
      const int b = boct + i;
      xl[b * 20 + (b >> 3) * 4 + kp] = (unsigned)(unsigned short)xa[i] |
                                       ((unsigned)(unsigned short)xb[i] << 16);
    }
  }
  __syncthreads();

  for (int t = 0; t < 32; ++t) {
    const int cur = t & 1;
    if (t < 31) {
      const unsigned short* wp = wsrc + (t + 1) * 32;
      wreg0 = *(const short8v*)(wp);
      wreg1 = *(const short8v*)(wp + 8);
      const unsigned short* xp = xsrc + (size_t)(t + 1) * 32 * B;
      xa = *(const short8v*)(xp);
      xb = *(const short8v*)(xp + B);
    }
    {
      short8v aw[2], bx[8];
#pragma unroll
      for (int jt = 0; jt < 2; ++jt)
        aw[jt] = *(const short8v*)&Wl[cur][(w * 32 + jt * 16 + m) * 40 + g * 8];
#pragma unroll
      for (int bt = 0; bt < 8; ++bt) {
        const int b = bt * 16 + m;
        bx[bt] = *(const short8v*)&Xl[cur][b * 40 + (b >> 3) * 8 + g * 8];
      }
#pragma unroll
      for (int jt = 0; jt < 2; ++jt)
#pragma unroll
        for (int bt = 0; bt < 8; ++bt)
          acc[jt][bt] = __builtin_amdgcn_mfma_f32_16x16x32_bf16(
              aw[jt], bx[bt], acc[jt][bt], 0, 0, 0);
    }
    if (t < 31) {
      const int nxt = cur ^ 1;
      *(short8v*)&Wl[nxt][wj * 40 + wkh] = wreg0;
      *(short8v*)&Wl[nxt][wj * 40 + wkh + 8] = wreg1;
      unsigned* xl = (unsigned*)&Xl[nxt][0];
#pragma unroll
      for (int i = 0; i < 8; ++i) {
        const int b = boct + i;
        xl[b * 20 + (b >> 3) * 4 + kp] =
            (unsigned)(unsigned short)xa[i] |
            ((unsigned)(unsigned short)xb[i] << 16);
      }
    }
    __syncthreads();
  }

#pragma unroll
  for (int jt = 0; jt < 2; ++jt)
#pragma unroll
    for (int r = 0; r < 4; ++r) {
      const int j = j0 + w * 32 + jt * 16 + g * 4 + r;
      const float bj = fb1[j];
#pragma unroll
      for (int bt = 0; bt < 8; ++bt)
        out[(size_t)j * B + b0 + bt * 16 + m] =
            f2bf(fmaxf(acc[jt][bt][r] + bj, 0.f));
    }
}

// ---------------- FC2: out[b,10] = fw2[10,512] @ h4[512,B] + fb2 -----------
__global__ __launch_bounds__(256) void k_fc2(
    const unsigned short* __restrict__ in, const float* __restrict__ fw2,
    const float* __restrict__ fb2, float* __restrict__ out, int B, int b0) {
  __shared__ float red[4][10][64];
  const int tx = threadIdx.x;
  const int b = blockIdx.x * 64 + tx;
  const int tyu = threadIdx.y;
  float acc[10];
#pragma unroll
  for (int i = 0; i < 10; ++i) acc[i] = 0.f;
  for (int kk = 0; kk < 128; ++kk) {
    const int k = tyu * 128 + kk;
    const float v = bf2f(in[(size_t)k * B + b]);
#pragma unroll
    for (int i = 0; i < 10; ++i) acc[i] = fmaf(v, fw2[i * 512 + k], acc[i]);
  }
#pragma unroll
  for (int i = 0; i < 10; ++i) red[tyu][i][tx] = acc[i];
  __syncthreads();
  if (threadIdx.y == 0) {
#pragma unroll
    for (int i = 0; i < 10; ++i) {
      const float s = fb2[i] + red[0][i][tx] + red[1][i][tx] + red[2][i][tx] +
                      red[3][i][tx];
      out[(size_t)(b0 + b) * 10 + i] = s;
    }
  }
}

extern "C" void kernel_launch(void* const* d_in, const int* in_sizes, int n_in,
                              void* d_out, int out_size, void* d_ws,
                              size_t ws_size, hipStream_t stream) {
  const float* x   = (const float*)d_in[0];
  const float* w1  = (const float*)d_in[1];
  const float* b1  = (const float*)d_in[2];
  const float* w2  = (const float*)d_in[3];
  const float* b2  = (const float*)d_in[4];
  const float* w3  = (const float*)d_in[5];
  const float* b3  = (const float*)d_in[6];
  const float* fw1 = (const float*)d_in[7];
  const float* fb1 = (const float*)d_in[8];
  const float* fw2 = (const float*)d_in[9];
  const float* fb2 = (const float*)d_in[10];
  float* out = (float*)d_out;

  const int B = in_sizes[0] / 784;  // 8192

  // ws (float units): Wm2[92160] | Wm3[147456] | Wbf[262144] | bf16 h-buffers
  const size_t nWm2 = (size_t)36 * 32 * 160 / 2;
  const size_t nWm3 = (size_t)16 * 64 * 288 / 2;
  const size_t nWbf = (size_t)512 * 1024 / 2;
  unsigned short* Wm2 = (unsigned short*)d_ws;
  unsigned short* Wm3 = (unsigned short*)((float*)d_ws + nWm2);
  unsigned short* Wbf = (unsigned short*)((float*)d_ws + nWm2 + nWm3);
  unsigned short* hbase = (unsigned short*)((float*)d_ws + nWm2 + nWm3 + nWbf);
  const size_t ws_rem = ws_size - (nWm2 + nWm3 + nWbf) * sizeof(float);

  // per-batch-element bf16 shorts: h1 2704 + h2 1152 + h3 1024 + h4 512
  const size_t per_elem = (size_t)(2704 + 1152 + 1024 + 512) * 2;
  int Bc = B;
  while ((size_t)Bc * per_elem > ws_rem && Bc > 512) Bc >>= 1;
  const int nch = B / Bc;

  unsigned short* H1 = hbase;
  unsigned short* H2 = H1 + (size_t)2704 * Bc;
  unsigned short* H3 = H2 + (size_t)1152 * Bc;
  unsigned short* H4 = H3 + (size_t)1024 * Bc;

  // one-time weight transforms
  k_wmc<32, 16, 36, 160><<<dim3(36, 32), 160, 0, stream>>>(w2, Wm2);
  k_wmc<64, 32, 16, 288><<<dim3(16, 64), 288, 0, stream>>>(w3, Wm3);
  k_wbf<<<dim3(256), 256, 0, stream>>>(fw1, Wbf);

  for (int ch = 0; ch < nch; ++ch) {
    const float* xc = x + (size_t)ch * Bc * 784;
    const int b0 = ch * Bc;

    // LC1 (fused transpose): x[B,784] -> h1[2704,Bc] bf16
    k_lc1<<<dim3(Bc / 64, 13), 256, 0, stream>>>(xc, w1, b1, H1, Bc);
    // LC2: h1 -> h2[1152,Bc] bf16
    k_lcm<32, 144, 36, 169, 13, 6, 2, true>
        <<<dim3(Bc / 128, 36), 256, 0, stream>>>(H1, Wm2, b2, H2, Bc);
    // LC3: h2 -> h3[1024,Bc] bf16
    k_lcm<64, 288, 16, 36, 6, 4, 1, false>
        <<<dim3(Bc / 128, 16), 256, 0, stream>>>(H2, Wm3, b3, H3, Bc);
    // FC1: h3 -> h4[512,Bc] bf16
    k_fc1m<<<dim3(Bc / 128, 4), 256, 0, stream>>>(H3, Wbf, fb1, H4, Bc);
    // FC2: h4 -> out[b,10] f32
    k_fc2<<<dim3(Bc / 64), dim3(64, 4), 0, stream>>>(H4, fw2, fb2, out, Bc,
                                                     b0);
  }
}

// Round 12
// 128.603 us; speedup vs baseline: 7.1484x; 1.0680x over previous
//
#include <hip/hip_runtime.h>

typedef __attribute__((ext_vector_type(8))) short short8v;   // 8 bf16
typedef __attribute__((ext_vector_type(4))) float f32x4;

static __device__ __forceinline__ unsigned short f2bf(float f) {
  union { float f; unsigned u; } v;
  v.f = f;
  const unsigned u = v.u;
  return (unsigned short)((u + 0x7FFF + ((u >> 16) & 1)) >> 16);  // RNE
}
static __device__ __forceinline__ float bf2f(unsigned short s) {
  union { unsigned u; float f; } v;
  v.u = ((unsigned)s) << 16;
  return v.f;
}

// Intermediates h1..h4 stored bf16 in [feature, B] layout (batch-last).

// ------- LC1 fused with input transpose: x[B,784] f32 -> h1[2704,B] bf16 ---
// grid (B/64, 13=ho), block 256. Weights for this ho staged to LDS (kills the
// R11 scalar-load serialization: 468 wave-uniform w-reads/thread were s_load
// chains; now ds_read broadcasts).
__global__ __launch_bounds__(256) void k_lc1(const float* __restrict__ x,
                                             const float* __restrict__ w,
                                             const float* __restrict__ bias,
                                             unsigned short* __restrict__ out,
                                             int B) {
  __shared__ float Xs[64][89];
  __shared__ float Ws[16 * 117];  // [o][wo*9+kk] for this ho (contig per o)
  __shared__ float Bs[208];       // [o*13+wo]
  const int tid = threadIdx.x;
  const int b0 = blockIdx.x * 64;
  const int ho = blockIdx.y;
  const int fbase = 2 * ho * 28;

  // stage weights: 16 contiguous 117-float chunks
  for (int i = tid; i < 16 * 117 / 3; i += 256) {  // 624 float3-ish: use plain
  }
  for (int i = tid; i < 1872; i += 256)
    Ws[i] = w[((size_t)(i / 117) * 169 + ho * 13) * 9 + (i % 117)];
  for (int i = tid; i < 208; i += 256)
    Bs[i] = bias[(i / 13) * 169 + ho * 13 + (i % 13)];

  for (int idx = tid; idx < 1344; idx += 256) {  // 64 b x 21 float4
    const int b = idx / 21, q = idx - b * 21;
    const float4 v =
        *(const float4*)&x[(size_t)(b0 + b) * 784 + fbase + q * 4];
    Xs[b][q * 4 + 0] = v.x;
    Xs[b][q * 4 + 1] = v.y;
    Xs[b][q * 4 + 2] = v.z;
    Xs[b][q * 4 + 3] = v.w;
  }
  __syncthreads();

  const int lane = tid & 63;
  const int o0 = (tid >> 6) * 4;
  float xv[3][27];
#pragma unroll
  for (int r = 0; r < 3; ++r)
#pragma unroll
    for (int col = 0; col < 27; ++col) xv[r][col] = Xs[lane][r * 28 + col];

  float acc[4][13];
#pragma unroll
  for (int oo = 0; oo < 4; ++oo)
#pragma unroll
    for (int wo = 0; wo < 13; ++wo) acc[oo][wo] = Bs[(o0 + oo) * 13 + wo];
#pragma unroll
  for (int oo = 0; oo < 4; ++oo)
#pragma unroll
    for (int wo = 0; wo < 13; ++wo) {
      const float* wp = &Ws[(o0 + oo) * 117 + wo * 9];
#pragma unroll
      for (int kh = 0; kh < 3; ++kh)
#pragma unroll
        for (int kw = 0; kw < 3; ++kw)
          acc[oo][wo] = fmaf(xv[kh][2 * wo + kw], wp[kh * 3 + kw], acc[oo][wo]);
    }
#pragma unroll
  for (int oo = 0; oo < 4; ++oo)
#pragma unroll
    for (int wo = 0; wo < 13; ++wo)
      out[(size_t)((o0 + oo) * 169 + ho * 13 + wo) * B + b0 + lane] =
          f2bf(fmaxf(acc[oo][wo], 0.f));
}

// ------ LC weight -> bf16 [pos][o][Kpad], zero-padded k >= K ---------------
template <int O, int C, int NPOS, int Kpad>
__global__ void k_wmc(const float* __restrict__ w,
                      unsigned short* __restrict__ wm) {
  const int pos = blockIdx.x, o = blockIdx.y, k = threadIdx.x;
  float v = 0.f;
  if (k < C * 9) {
    const int c = k / 9, kk = k - c * 9;
    v = w[((size_t)(o * C + c) * NPOS + pos) * 9 + kk];
  }
  wm[((size_t)pos * O + o) * Kpad + k] = f2bf(v);
}

// ---------------- fw1 -> bf16 copy (once) ----------------------------------
__global__ __launch_bounds__(256) void k_wbf(const float* __restrict__ w,
                                             unsigned short* __restrict__ o) {
  const int i = (blockIdx.x * 256 + threadIdx.x) * 8;
  const float4 a = *(const float4*)&w[i];
  const float4 b = *(const float4*)&w[i + 4];
  short8v r;
  r[0] = (short)f2bf(a.x); r[1] = (short)f2bf(a.y);
  r[2] = (short)f2bf(a.z); r[3] = (short)f2bf(a.w);
  r[4] = (short)f2bf(b.x); r[5] = (short)f2bf(b.y);
  r[6] = (short)f2bf(b.z); r[7] = (short)f2bf(b.w);
  *(short8v*)&o[i] = r;
}

// ---------------- LC layer via bf16 MFMA (bf16 in, bf16 out) ---------------
template <int O, int K, int NPOS, int HWIN, int WIN, int WOD, int STR,
          bool RELU>
__global__ __launch_bounds__(256) void k_lcm(
    const unsigned short* __restrict__ X, const unsigned short* __restrict__ Wm,
    const float* __restrict__ bias, unsigned short* __restrict__ out, int B) {
  constexpr int NSTEP = (K + 31) / 32;
  constexpr int Kpad = NSTEP * 32;
  constexpr int NBT = (O == 64) ? 8 : 4;  // b-tiles per wave
  __shared__ short Wl[2][O * 40];
  __shared__ short Xl[2][5232];
  __shared__ int rowtab[Kpad];
  const int tid = threadIdx.x;
  const int b0 = blockIdx.x * 128;
  const int pos = blockIdx.y;
  const int ho = pos / WOD, wo = pos - ho * WOD;
  const int w = tid >> 6, l = tid & 63, m = l & 15, g = l >> 4;
  const int jw = (O == 64) ? w * 16 : (w & 1) * 16;
  const int boff = (O == 64) ? 0 : (w >> 1) * 64;

  for (int k = tid; k < Kpad; k += 256) {
    int r = 0;
    if (k < K) {
      const int c = k / 9, kk = k - c * 9;
      const int kh = kk / 3, kw = kk - kh * 3;
      r = c * HWIN + (ho * STR + kh) * WIN + (wo * STR + kw);
    }
    rowtab[k] = r;
  }
  __syncthreads();

  const unsigned short* wsrc = Wm + (size_t)pos * O * Kpad;
  const int wjj = tid >> 2, wko = (tid & 3) * 8;
  const bool wact = tid < O * 4;
  const int kp = tid >> 4, boct = (tid & 15) * 8;

  f32x4 acc[NBT];
#pragma unroll
  for (int bt = 0; bt < NBT; ++bt) acc[bt] = (f32x4){0.f, 0.f, 0.f, 0.f};

  short8v wreg, xa, xb;
  bool z0, z1;

  // ---- load chunk 0
  if (wact) wreg = *(const short8v*)&wsrc[(size_t)wjj * Kpad + wko];
  {
    const int k0 = 2 * kp;
    z0 = k0 >= K;
    z1 = k0 + 1 >= K;
    xa = *(const short8v*)(X + (size_t)rowtab[k0] * B + b0 + boct);
    xb = *(const short8v*)(X + (size_t)rowtab[k0 + 1] * B + b0 + boct);
  }
  // ---- write buf 0
  if (wact) *(short8v*)&Wl[0][wjj * 40 + wko] = wreg;
  {
    unsigned* xl = (unsigned*)&Xl[0][0];
#pragma unroll
    for (int i = 0; i < 8; ++i) {
      const int b = boct + i;
      const unsigned lo = z0 ? 0u : (unsigned)(unsigned short)xa[i];
      const unsigned hi = z1 ? 0u : (unsigned)(unsigned short)xb[i];
      xl[b * 20 + (b >> 3) * 4 + kp] = lo | (hi << 16);
    }
  }
  __syncthreads();

  for (int t = 0; t < NSTEP; ++t) {
    const int cur = t & 1;
    if (t < NSTEP - 1) {
      const int kc = (t + 1) * 32;
      if (wact) wreg = *(const short8v*)&wsrc[(size_t)wjj * Kpad + kc + wko];
      const int k0 = kc + 2 * kp;
      z0 = k0 >= K;
      z1 = k0 + 1 >= K;
      xa = *(const short8v*)(X + (size_t)rowtab[k0] * B + b0 + boct);
      xb = *(const short8v*)(X + (size_t)rowtab[k0 + 1] * B + b0 + boct);
    }
    {
      const short8v aw = *(const short8v*)&Wl[cur][(jw + m) * 40 + g * 8];
      short8v bx[NBT];
#pragma unroll
      for (int bt = 0; bt < NBT; ++bt) {
        const int b = boff + bt * 16 + m;
        bx[bt] = *(const short8v*)&Xl[cur][b * 40 + (b >> 3) * 8 + g * 8];
      }
#pragma unroll
      for (int bt = 0; bt < NBT; ++bt)
        acc[bt] = __builtin_amdgcn_mfma_f32_16x16x32_bf16(aw, bx[bt], acc[bt],
                                                          0, 0, 0);
    }
    if (t < NSTEP - 1) {
      const int nxt = cur ^ 1;
      if (wact) *(short8v*)&Wl[nxt][wjj * 40 + wko] = wreg;
      unsigned* xl = (unsigned*)&Xl[nxt][0];
#pragma unroll
      for (int i = 0; i < 8; ++i) {
        const int b = boct + i;
        const unsigned lo = z0 ? 0u : (unsigned)(unsigned short)xa[i];
        const unsigned hi = z1 ? 0u : (unsigned)(unsigned short)xb[i];
        xl[b * 20 + (b >> 3) * 4 + kp] = lo | (hi << 16);
      }
    }
    __syncthreads();
  }

  // ---- epilogue: D col=lane&15 (b), row=g*4+r (o); f = o*NPOS + pos
#pragma unroll
  for (int r = 0; r < 4; ++r) {
    const int o = jw + g * 4 + r;
    const int f = o * NPOS + pos;
    const float bz = bias[f];
#pragma unroll
    for (int bt = 0; bt < NBT; ++bt) {
      float v = acc[bt][r] + bz;
      if (RELU) v = fmaxf(v, 0.f);
      out[(size_t)f * B + b0 + boff + bt * 16 + m] = f2bf(v);
    }
  }
}

// ---------------- FC1 via bf16 MFMA (bf16 in, bf16 out) --------------------
__global__ __launch_bounds__(256) void k_fc1m(
    const unsigned short* __restrict__ X,
    const unsigned short* __restrict__ Wbf, const float* __restrict__ fb1,
    unsigned short* __restrict__ out, int B) {
  __shared__ short Wl[2][5120];   // 128 rows x 40 shorts
  __shared__ short Xl[2][5232];   // 128 rows x 40 + monotone stagger
  const int tid = threadIdx.x;
  const int b0 = blockIdx.x * 128, j0 = blockIdx.y * 128;
  const int w = tid >> 6, l = tid & 63, m = l & 15, g = l >> 4;

  const int wj = tid >> 1, wkh = (tid & 1) * 16;
  const unsigned short* wsrc = Wbf + (size_t)(j0 + wj) * 1024 + wkh;
  const int kp = tid >> 4, boct = (tid & 15) * 8;
  const unsigned short* xsrc = X + (size_t)(2 * kp) * B + b0 + boct;

  f32x4 acc[2][8];
#pragma unroll
  for (int jt = 0; jt < 2; ++jt)
#pragma unroll
    for (int bt = 0; bt < 8; ++bt) acc[jt][bt] = (f32x4){0.f, 0.f, 0.f, 0.f};

  short8v wreg0, wreg1, xa, xb;

  wreg0 = *(const short8v*)(wsrc);
  wreg1 = *(const short8v*)(wsrc + 8);
  xa = *(const short8v*)(xsrc);
  xb = *(const short8v*)(xsrc + B);

  {
    *(short8v*)&Wl[0][wj * 40 + wkh] = wreg0;
    *(short8v*)&Wl[0][wj * 40 + wkh + 8] = wreg1;
    unsigned* xl = (unsigned*)&Xl[0][0];
#pragma unroll
    for (int i = 0; i < 8; ++i) {
      const int b = boct + i;
      xl[b * 20 + (b >> 3) * 4 + kp] = (unsigned)(unsigned short)xa[i] |
                                       ((unsigned)(unsigned short)xb[i] << 16);
    }
  }
  __syncthreads();

  for (int t = 0; t < 32; ++t) {
    const int cur = t & 1;
    if (t < 31) {
      const unsigned short* wp = wsrc + (t + 1) * 32;
      wreg0 = *(const short8v*)(wp);
      wreg1 = *(const short8v*)(wp + 8);
      const unsigned short* xp = xsrc + (size_t)(t + 1) * 32 * B;
      xa = *(const short8v*)(xp);
      xb = *(const short8v*)(xp + B);
    }
    {
      short8v aw[2], bx[8];
#pragma unroll
      for (int jt = 0; jt < 2; ++jt)
        aw[jt] = *(const short8v*)&Wl[cur][(w * 32 + jt * 16 + m) * 40 + g * 8];
#pragma unroll
      for (int bt = 0; bt < 8; ++bt) {
        const int b = bt * 16 + m;
        bx[bt] = *(const short8v*)&Xl[cur][b * 40 + (b >> 3) * 8 + g * 8];
      }
#pragma unroll
      for (int jt = 0; jt < 2; ++jt)
#pragma unroll
        for (int bt = 0; bt < 8; ++bt)
          acc[jt][bt] = __builtin_amdgcn_mfma_f32_16x16x32_bf16(
              aw[jt], bx[bt], acc[jt][bt], 0, 0, 0);
    }
    if (t < 31) {
      const int nxt = cur ^ 1;
      *(short8v*)&Wl[nxt][wj * 40 + wkh] = wreg0;
      *(short8v*)&Wl[nxt][wj * 40 + wkh + 8] = wreg1;
      unsigned* xl = (unsigned*)&Xl[nxt][0];
#pragma unroll
      for (int i = 0; i < 8; ++i) {
        const int b = boct + i;
        xl[b * 20 + (b >> 3) * 4 + kp] =
            (unsigned)(unsigned short)xa[i] |
            ((unsigned)(unsigned short)xb[i] << 16);
      }
    }
    __syncthreads();
  }

#pragma unroll
  for (int jt = 0; jt < 2; ++jt)
#pragma unroll
    for (int r = 0; r < 4; ++r) {
      const int j = j0 + w * 32 + jt * 16 + g * 4 + r;
      const float bj = fb1[j];
#pragma unroll
      for (int bt = 0; bt < 8; ++bt)
        out[(size_t)j * B + b0 + bt * 16 + m] =
            f2bf(fmaxf(acc[jt][bt][r] + bj, 0.f));
    }
}

// ---------------- FC2: out[b,10] = fw2[10,512] @ h4[512,B] + fb2 -----------
__global__ __launch_bounds__(256) void k_fc2(
    const unsigned short* __restrict__ in, const float* __restrict__ fw2,
    const float* __restrict__ fb2, float* __restrict__ out, int B, int b0) {
  __shared__ float red[4][10][64];
  const int tx = threadIdx.x;
  const int b = blockIdx.x * 64 + tx;
  const int tyu = threadIdx.y;
  float acc[10];
#pragma unroll
  for (int i = 0; i < 10; ++i) acc[i] = 0.f;
  for (int kk = 0; kk < 128; ++kk) {
    const int k = tyu * 128 + kk;
    const float v = bf2f(in[(size_t)k * B + b]);
#pragma unroll
    for (int i = 0; i < 10; ++i) acc[i] = fmaf(v, fw2[i * 512 + k], acc[i]);
  }
#pragma unroll
  for (int i = 0; i < 10; ++i) red[tyu][i][tx] = acc[i];
  __syncthreads();
  if (threadIdx.y == 0) {
#pragma unroll
    for (int i = 0; i < 10; ++i) {
      const float s = fb2[i] + red[0][i][tx] + red[1][i][tx] + red[2][i][tx] +
                      red[3][i][tx];
      out[(size_t)(b0 + b) * 10 + i] = s;
    }
  }
}

extern "C" void kernel_launch(void* const* d_in, const int* in_sizes, int n_in,
                              void* d_out, int out_size, void* d_ws,
                              size_t ws_size, hipStream_t stream) {
  const float* x   = (const float*)d_in[0];
  const float* w1  = (const float*)d_in[1];
  const float* b1  = (const float*)d_in[2];
  const float* w2  = (const float*)d_in[3];
  const float* b2  = (const float*)d_in[4];
  const float* w3  = (const float*)d_in[5];
  const float* b3  = (const float*)d_in[6];
  const float* fw1 = (const float*)d_in[7];
  const float* fb1 = (const float*)d_in[8];
  const float* fw2 = (const float*)d_in[9];
  const float* fb2 = (const float*)d_in[10];
  float* out = (float*)d_out;

  const int B = in_sizes[0] / 784;  // 8192

  // ws (float units): Wm2[92160] | Wm3[147456] | Wbf[262144] | bf16 h-buffers
  const size_t nWm2 = (size_t)36 * 32 * 160 / 2;
  const size_t nWm3 = (size_t)16 * 64 * 288 / 2;
  const size_t nWbf = (size_t)512 * 1024 / 2;
  unsigned short* Wm2 = (unsigned short*)d_ws;
  unsigned short* Wm3 = (unsigned short*)((float*)d_ws + nWm2);
  unsigned short* Wbf = (unsigned short*)((float*)d_ws + nWm2 + nWm3);
  unsigned short* hbase = (unsigned short*)((float*)d_ws + nWm2 + nWm3 + nWbf);
  const size_t ws_rem = ws_size - (nWm2 + nWm3 + nWbf) * sizeof(float);

  // per-batch-element bf16 shorts: h1 2704 + h2 1152 + h3 1024 + h4 512
  const size_t per_elem = (size_t)(2704 + 1152 + 1024 + 512) * 2;
  int Bc = B;
  while ((size_t)Bc * per_elem > ws_rem && Bc > 512) Bc >>= 1;
  const int nch = B / Bc;

  unsigned short* H1 = hbase;
  unsigned short* H2 = H1 + (size_t)2704 * Bc;
  unsigned short* H3 = H2 + (size_t)1152 * Bc;
  unsigned short* H4 = H3 + (size_t)1024 * Bc;

  // one-time weight transforms
  k_wmc<32, 16, 36, 160><<<dim3(36, 32), 160, 0, stream>>>(w2, Wm2);
  k_wmc<64, 32, 16, 288><<<dim3(16, 64), 288, 0, stream>>>(w3, Wm3);
  k_wbf<<<dim3(256), 256, 0, stream>>>(fw1, Wbf);

  for (int ch = 0; ch < nch; ++ch) {
    const float* xc = x + (size_t)ch * Bc * 784;
    const int b0 = ch * Bc;

    // LC1 (fused transpose): x[B,784] -> h1[2704,Bc] bf16
    k_lc1<<<dim3(Bc / 64, 13), 256, 0, stream>>>(xc, w1, b1, H1, Bc);
    // LC2: h1 -> h2[1152,Bc] bf16
    k_lcm<32, 144, 36, 169, 13, 6, 2, true>
        <<<dim3(Bc / 128, 36), 256, 0, stream>>>(H1, Wm2, b2, H2, Bc);
    // LC3: h2 -> h3[1024,Bc] bf16
    k_lcm<64, 288, 16, 36, 6, 4, 1, false>
        <<<dim3(Bc / 128, 16), 256, 0, stream>>>(H2, Wm3, b3, H3, Bc);
    // FC1: h3 -> h4[512,Bc] bf16
    k_fc1m<<<dim3(Bc / 128, 4), 256, 0, stream>>>(H3, Wbf, fb1, H4, Bc);
    // FC2: h4 -> out[b,10] f32
    k_fc2<<<dim3(Bc / 64), dim3(64, 4), 0, stream>>>(H4, fw2, fb2, out, Bc,
                                                     b0);
  }
}

// Round 13
// 122.585 us; speedup vs baseline: 7.4993x; 1.0491x over previous
//
#include <hip/hip_runtime.h>

typedef __attribute__((ext_vector_type(8))) short short8v;   // 8 bf16
typedef __attribute__((ext_vector_type(4))) float f32x4;

static __device__ __forceinline__ unsigned short f2bf(float f) {
  union { float f; unsigned u; } v;
  v.f = f;
  const unsigned u = v.u;
  return (unsigned short)((u + 0x7FFF + ((u >> 16) & 1)) >> 16);  // RNE
}
static __device__ __forceinline__ float bf2f(unsigned short s) {
  union { unsigned u; float f; } v;
  v.u = ((unsigned)s) << 16;
  return v.f;
}

// Intermediates h1..h4 stored bf16 in [feature, B] layout (batch-last).

// ------ w1 -> bf16 [pos][o][32k] zero-padded (once) ------------------------
__global__ void k_wm1(const float* __restrict__ w,
                      unsigned short* __restrict__ wm) {
  const int pos = blockIdx.x, o = blockIdx.y, k = threadIdx.x;  // 32 thr
  const float v = (k < 9) ? w[((size_t)o * 169 + pos) * 9 + k] : 0.f;
  wm[((size_t)pos * 16 + o) * 32 + k] = f2bf(v);
}

// ------- LC1 via MFMA: x[B,784] f32 -> h1[2704,B] bf16 ---------------------
// Block = (ho, 128 b). Each of 13 wo is a 16o x 9k GEMM; K padded 9->32 so
// ONE mfma_16x16x32 per (wo, 16-b tile) — no K loop. Replaces R12's 468
// per-thread ds_read_b32 weight reads (LDS *issue*-bound, ~35 us/CU) with
// 8 ds_read_u16 per B-frag + 1 ds_read_b128 per A-frag.
__global__ __launch_bounds__(256) void k_lc1m(
    const float* __restrict__ x, const unsigned short* __restrict__ Wm1,
    const float* __restrict__ bias, unsigned short* __restrict__ out, int B) {
  __shared__ unsigned short Xl[109 * 130];  // [e 0..83 | zero 84..108][b]
  __shared__ unsigned short Wl[13 * 16 * 40];
  __shared__ float Bs[208];
  const int tid = threadIdx.x;
  const int b0 = blockIdx.x * 128;
  const int ho = blockIdx.y;
  const int wv = tid >> 6, l = tid & 63, m = l & 15, g = l >> 4;

  // zero pad rows 84..108
  unsigned* xl32 = (unsigned*)Xl;
  for (int i = tid; i < 25 * 65; i += 256) xl32[84 * 65 + i] = 0;
  // im2col stage: window element e=0..83 of this ho -> Xl[e][b]
  const int fbase = 2 * ho * 28;
  for (int idx = tid; idx < 2688; idx += 256) {
    const int b = idx / 21, q = idx - b * 21;
    const float4 v =
        *(const float4*)&x[(size_t)(b0 + b) * 784 + fbase + q * 4];
    const int e = q * 4;
    Xl[(e + 0) * 130 + b] = f2bf(v.x);
    Xl[(e + 1) * 130 + b] = f2bf(v.y);
    Xl[(e + 2) * 130 + b] = f2bf(v.z);
    Xl[(e + 3) * 130 + b] = f2bf(v.w);
  }
  // stage weights (40-short row stride for bank spread)
  for (int idx = tid; idx < 832; idx += 256) {
    const int wo = idx >> 6, rem = idx & 63;
    const int o = rem >> 2, s = rem & 3;
    *(short8v*)&Wl[(wo * 16 + o) * 40 + s * 8] =
        *(const short8v*)&Wm1[((size_t)(ho * 13 + wo) * 16 + o) * 32 + s * 8];
  }
  for (int i = tid; i < 208; i += 256)
    Bs[i] = bias[(i / 13) * 169 + ho * 13 + (i % 13)];
  __syncthreads();

  // per-lane B-frag bases: k = g*8+i -> window element e (84 = zero row)
  int rbase[8];
#pragma unroll
  for (int i = 0; i < 8; ++i) {
    const int k = g * 8 + i;
    const int kh = k / 3;
    const int e = (k < 9) ? kh * 28 + (k - kh * 3) : 84;
    rbase[i] = e * 130 + wv * 32 + m;
  }

#pragma unroll
  for (int wo = 0; wo < 13; ++wo) {
    const short8v aw = *(const short8v*)&Wl[(wo * 16 + m) * 40 + g * 8];
#pragma unroll
    for (int nt = 0; nt < 2; ++nt) {
      short8v bx;
#pragma unroll
      for (int i = 0; i < 8; ++i)
        bx[i] = (short)Xl[rbase[i] + wo * 260 + nt * 16];
      const f32x4 acc = __builtin_amdgcn_mfma_f32_16x16x32_bf16(
          aw, bx, (f32x4){0.f, 0.f, 0.f, 0.f}, 0, 0, 0);
#pragma unroll
      for (int r = 0; r < 4; ++r) {
        const int o = g * 4 + r;
        const float vv = fmaxf(acc[r] + Bs[o * 13 + wo], 0.f);
        out[(size_t)(o * 169 + ho * 13 + wo) * B + b0 + wv * 32 + nt * 16 +
            m] = f2bf(vv);
      }
    }
  }
}

// ------ LC weight -> bf16 [pos][o][Kpad], zero-padded k >= K ---------------
template <int O, int C, int NPOS, int Kpad>
__global__ void k_wmc(const float* __restrict__ w,
                      unsigned short* __restrict__ wm) {
  const int pos = blockIdx.x, o = blockIdx.y, k = threadIdx.x;
  float v = 0.f;
  if (k < C * 9) {
    const int c = k / 9, kk = k - c * 9;
    v = w[((size_t)(o * C + c) * NPOS + pos) * 9 + kk];
  }
  wm[((size_t)pos * O + o) * Kpad + k] = f2bf(v);
}

// ---------------- fw1 -> bf16 copy (once) ----------------------------------
__global__ __launch_bounds__(256) void k_wbf(const float* __restrict__ w,
                                             unsigned short* __restrict__ o) {
  const int i = (blockIdx.x * 256 + threadIdx.x) * 8;
  const float4 a = *(const float4*)&w[i];
  const float4 b = *(const float4*)&w[i + 4];
  short8v r;
  r[0] = (short)f2bf(a.x); r[1] = (short)f2bf(a.y);
  r[2] = (short)f2bf(a.z); r[3] = (short)f2bf(a.w);
  r[4] = (short)f2bf(b.x); r[5] = (short)f2bf(b.y);
  r[6] = (short)f2bf(b.z); r[7] = (short)f2bf(b.w);
  *(short8v*)&o[i] = r;
}

// ---------------- LC layer via bf16 MFMA (bf16 in, bf16 out) ---------------
template <int O, int K, int NPOS, int HWIN, int WIN, int WOD, int STR,
          bool RELU>
__global__ __launch_bounds__(256) void k_lcm(
    const unsigned short* __restrict__ X, const unsigned short* __restrict__ Wm,
    const float* __restrict__ bias, unsigned short* __restrict__ out, int B) {
  constexpr int NSTEP = (K + 31) / 32;
  constexpr int Kpad = NSTEP * 32;
  constexpr int NBT = (O == 64) ? 8 : 4;  // b-tiles per wave
  __shared__ short Wl[2][O * 40];
  __shared__ short Xl[2][5232];
  __shared__ int rowtab[Kpad];
  const int tid = threadIdx.x;
  const int b0 = blockIdx.x * 128;
  const int pos = blockIdx.y;
  const int ho = pos / WOD, wo = pos - ho * WOD;
  const int w = tid >> 6, l = tid & 63, m = l & 15, g = l >> 4;
  const int jw = (O == 64) ? w * 16 : (w & 1) * 16;
  const int boff = (O == 64) ? 0 : (w >> 1) * 64;

  for (int k = tid; k < Kpad; k += 256) {
    int r = 0;
    if (k < K) {
      const int c = k / 9, kk = k - c * 9;
      const int kh = kk / 3, kw = kk - kh * 3;
      r = c * HWIN + (ho * STR + kh) * WIN + (wo * STR + kw);
    }
    rowtab[k] = r;
  }
  __syncthreads();

  const unsigned short* wsrc = Wm + (size_t)pos * O * Kpad;
  const int wjj = tid >> 2, wko = (tid & 3) * 8;
  const bool wact = tid < O * 4;
  const int kp = tid >> 4, boct = (tid & 15) * 8;

  f32x4 acc[NBT];
#pragma unroll
  for (int bt = 0; bt < NBT; ++bt) acc[bt] = (f32x4){0.f, 0.f, 0.f, 0.f};

  short8v wreg, xa, xb;
  bool z0, z1;

  if (wact) wreg = *(const short8v*)&wsrc[(size_t)wjj * Kpad + wko];
  {
    const int k0 = 2 * kp;
    z0 = k0 >= K;
    z1 = k0 + 1 >= K;
    xa = *(const short8v*)(X + (size_t)rowtab[k0] * B + b0 + boct);
    xb = *(const short8v*)(X + (size_t)rowtab[k0 + 1] * B + b0 + boct);
  }
  if (wact) *(short8v*)&Wl[0][wjj * 40 + wko] = wreg;
  {
    unsigned* xl = (unsigned*)&Xl[0][0];
#pragma unroll
    for (int i = 0; i < 8; ++i) {
      const int b = boct + i;
      const unsigned lo = z0 ? 0u : (unsigned)(unsigned short)xa[i];
      const unsigned hi = z1 ? 0u : (unsigned)(unsigned short)xb[i];
      xl[b * 20 + (b >> 3) * 4 + kp] = lo | (hi << 16);
    }
  }
  __syncthreads();

  for (int t = 0; t < NSTEP; ++t) {
    const int cur = t & 1;
    if (t < NSTEP - 1) {
      const int kc = (t + 1) * 32;
      if (wact) wreg = *(const short8v*)&wsrc[(size_t)wjj * Kpad + kc + wko];
      const int k0 = kc + 2 * kp;
      z0 = k0 >= K;
      z1 = k0 + 1 >= K;
      xa = *(const short8v*)(X + (size_t)rowtab[k0] * B + b0 + boct);
      xb = *(const short8v*)(X + (size_t)rowtab[k0 + 1] * B + b0 + boct);
    }
    {
      const short8v aw = *(const short8v*)&Wl[cur][(jw + m) * 40 + g * 8];
      short8v bx[NBT];
#pragma unroll
      for (int bt = 0; bt < NBT; ++bt) {
        const int b = boff + bt * 16 + m;
        bx[bt] = *(const short8v*)&Xl[cur][b * 40 + (b >> 3) * 8 + g * 8];
      }
#pragma unroll
      for (int bt = 0; bt < NBT; ++bt)
        acc[bt] = __builtin_amdgcn_mfma_f32_16x16x32_bf16(aw, bx[bt], acc[bt],
                                                          0, 0, 0);
    }
    if (t < NSTEP - 1) {
      const int nxt = cur ^ 1;
      if (wact) *(short8v*)&Wl[nxt][wjj * 40 + wko] = wreg;
      unsigned* xl = (unsigned*)&Xl[nxt][0];
#pragma unroll
      for (int i = 0; i < 8; ++i) {
        const int b = boct + i;
        const unsigned lo = z0 ? 0u : (unsigned)(unsigned short)xa[i];
        const unsigned hi = z1 ? 0u : (unsigned)(unsigned short)xb[i];
        xl[b * 20 + (b >> 3) * 4 + kp] = lo | (hi << 16);
      }
    }
    __syncthreads();
  }

#pragma unroll
  for (int r = 0; r < 4; ++r) {
    const int o = jw + g * 4 + r;
    const int f = o * NPOS + pos;
    const float bz = bias[f];
#pragma unroll
    for (int bt = 0; bt < NBT; ++bt) {
      float v = acc[bt][r] + bz;
      if (RELU) v = fmaxf(v, 0.f);
      out[(size_t)f * B + b0 + boff + bt * 16 + m] = f2bf(v);
    }
  }
}

// ---------------- FC1 via bf16 MFMA (bf16 in, bf16 out) --------------------
__global__ __launch_bounds__(256) void k_fc1m(
    const unsigned short* __restrict__ X,
    const unsigned short* __restrict__ Wbf, const float* __restrict__ fb1,
    unsigned short* __restrict__ out, int B) {
  __shared__ short Wl[2][5120];
  __shared__ short Xl[2][5232];
  const int tid = threadIdx.x;
  const int b0 = blockIdx.x * 128, j0 = blockIdx.y * 128;
  const int w = tid >> 6, l = tid & 63, m = l & 15, g = l >> 4;

  const int wj = tid >> 1, wkh = (tid & 1) * 16;
  const unsigned short* wsrc = Wbf + (size_t)(j0 + wj) * 1024 + wkh;
  const int kp = tid >> 4, boct = (tid & 15) * 8;
  const unsigned short* xsrc = X + (size_t)(2 * kp) * B + b0 + boct;

  f32x4 acc[2][8];
#pragma unroll
  for (int jt = 0; jt < 2; ++jt)
#pragma unroll
    for (int bt = 0; bt < 8; ++bt) acc[jt][bt] = (f32x4){0.f, 0.f, 0.f, 0.f};

  short8v wreg0, wreg1, xa, xb;

  wreg0 = *(const short8v*)(wsrc);
  wreg1 = *(const short8v*)(wsrc + 8);
  xa = *(const short8v*)(xsrc);
  xb = *(const short8v*)(xsrc + B);

  {
    *(short8v*)&Wl[0][wj * 40 + wkh] = wreg0;
    *(short8v*)&Wl[0][wj * 40 + wkh + 8] = wreg1;
    unsigned* xl = (unsigned*)&Xl[0][0];
#pragma unroll
    for (int i = 0; i < 8; ++i) {
      const int b = boct + i;
      xl[b * 20 + (b >> 3) * 4 + kp] = (unsigned)(unsigned short)xa[i] |
                                       ((unsigned)(unsigned short)xb[i] << 16);
    }
  }
  __syncthreads();

  for (int t = 0; t < 32; ++t) {
    const int cur = t & 1;
    if (t < 31) {
      const unsigned short* wp = wsrc + (t + 1) * 32;
      wreg0 = *(const short8v*)(wp);
      wreg1 = *(const short8v*)(wp + 8);
      const unsigned short* xp = xsrc + (size_t)(t + 1) * 32 * B;
      xa = *(const short8v*)(xp);
      xb = *(const short8v*)(xp + B);
    }
    {
      short8v aw[2], bx[8];
#pragma unroll
      for (int jt = 0; jt < 2; ++jt)
        aw[jt] = *(const short8v*)&Wl[cur][(w * 32 + jt * 16 + m) * 40 + g * 8];
#pragma unroll
      for (int bt = 0; bt < 8; ++bt) {
        const int b = bt * 16 + m;
        bx[bt] = *(const short8v*)&Xl[cur][b * 40 + (b >> 3) * 8 + g * 8];
      }
#pragma unroll
      for (int jt = 0; jt < 2; ++jt)
#pragma unroll
        for (int bt = 0; bt < 8; ++bt)
          acc[jt][bt] = __builtin_amdgcn_mfma_f32_16x16x32_bf16(
              aw[jt], bx[bt], acc[jt][bt], 0, 0, 0);
    }
    if (t < 31) {
      const int nxt = cur ^ 1;
      *(short8v*)&Wl[nxt][wj * 40 + wkh] = wreg0;
      *(short8v*)&Wl[nxt][wj * 40 + wkh + 8] = wreg1;
      unsigned* xl = (unsigned*)&Xl[nxt][0];
#pragma unroll
      for (int i = 0; i < 8; ++i) {
        const int b = boct + i;
        xl[b * 20 + (b >> 3) * 4 + kp] =
            (unsigned)(unsigned short)xa[i] |
            ((unsigned)(unsigned short)xb[i] << 16);
      }
    }
    __syncthreads();
  }

#pragma unroll
  for (int jt = 0; jt < 2; ++jt)
#pragma unroll
    for (int r = 0; r < 4; ++r) {
      const int j = j0 + w * 32 + jt * 16 + g * 4 + r;
      const float bj = fb1[j];
#pragma unroll
      for (int bt = 0; bt < 8; ++bt)
        out[(size_t)j * B + b0 + bt * 16 + m] =
            f2bf(fmaxf(acc[jt][bt][r] + bj, 0.f));
    }
}

// ---------------- FC2: out[b,10] = fw2[10,512] @ h4[512,B] + fb2 -----------
__global__ __launch_bounds__(256) void k_fc2(
    const unsigned short* __restrict__ in, const float* __restrict__ fw2,
    const float* __restrict__ fb2, float* __restrict__ out, int B, int b0) {
  __shared__ float red[4][10][64];
  const int tx = threadIdx.x;
  const int b = blockIdx.x * 64 + tx;
  const int tyu = threadIdx.y;
  float acc[10];
#pragma unroll
  for (int i = 0; i < 10; ++i) acc[i] = 0.f;
  for (int kk = 0; kk < 128; ++kk) {
    const int k = tyu * 128 + kk;
    const float v = bf2f(in[(size_t)k * B + b]);
#pragma unroll
    for (int i = 0; i < 10; ++i) acc[i] = fmaf(v, fw2[i * 512 + k], acc[i]);
  }
#pragma unroll
  for (int i = 0; i < 10; ++i) red[tyu][i][tx] = acc[i];
  __syncthreads();
  if (threadIdx.y == 0) {
#pragma unroll
    for (int i = 0; i < 10; ++i) {
      const float s = fb2[i] + red[0][i][tx] + red[1][i][tx] + red[2][i][tx] +
                      red[3][i][tx];
      out[(size_t)(b0 + b) * 10 + i] = s;
    }
  }
}

extern "C" void kernel_launch(void* const* d_in, const int* in_sizes, int n_in,
                              void* d_out, int out_size, void* d_ws,
                              size_t ws_size, hipStream_t stream) {
  const float* x   = (const float*)d_in[0];
  const float* w1  = (const float*)d_in[1];
  const float* b1  = (const float*)d_in[2];
  const float* w2  = (const float*)d_in[3];
  const float* b2  = (const float*)d_in[4];
  const float* w3  = (const float*)d_in[5];
  const float* b3  = (const float*)d_in[6];
  const float* fw1 = (const float*)d_in[7];
  const float* fb1 = (const float*)d_in[8];
  const float* fw2 = (const float*)d_in[9];
  const float* fb2 = (const float*)d_in[10];
  float* out = (float*)d_out;

  const int B = in_sizes[0] / 784;  // 8192

  // ws (float units): Wm1[43264] | Wm2[92160] | Wm3[147456] | Wbf[262144] | h
  const size_t nWm1 = (size_t)169 * 16 * 32 / 2;
  const size_t nWm2 = (size_t)36 * 32 * 160 / 2;
  const size_t nWm3 = (size_t)16 * 64 * 288 / 2;
  const size_t nWbf = (size_t)512 * 1024 / 2;
  unsigned short* Wm1 = (unsigned short*)d_ws;
  unsigned short* Wm2 = (unsigned short*)((float*)d_ws + nWm1);
  unsigned short* Wm3 = (unsigned short*)((float*)d_ws + nWm1 + nWm2);
  unsigned short* Wbf = (unsigned short*)((float*)d_ws + nWm1 + nWm2 + nWm3);
  unsigned short* hbase =
      (unsigned short*)((float*)d_ws + nWm1 + nWm2 + nWm3 + nWbf);
  const size_t ws_rem =
      ws_size - (nWm1 + nWm2 + nWm3 + nWbf) * sizeof(float);

  const size_t per_elem = (size_t)(2704 + 1152 + 1024 + 512) * 2;
  int Bc = B;
  while ((size_t)Bc * per_elem > ws_rem && Bc > 512) Bc >>= 1;
  const int nch = B / Bc;

  unsigned short* H1 = hbase;
  unsigned short* H2 = H1 + (size_t)2704 * Bc;
  unsigned short* H3 = H2 + (size_t)1152 * Bc;
  unsigned short* H4 = H3 + (size_t)1024 * Bc;

  // one-time weight transforms
  k_wm1<<<dim3(169, 16), 32, 0, stream>>>(w1, Wm1);
  k_wmc<32, 16, 36, 160><<<dim3(36, 32), 160, 0, stream>>>(w2, Wm2);
  k_wmc<64, 32, 16, 288><<<dim3(16, 64), 288, 0, stream>>>(w3, Wm3);
  k_wbf<<<dim3(256), 256, 0, stream>>>(fw1, Wbf);

  for (int ch = 0; ch < nch; ++ch) {
    const float* xc = x + (size_t)ch * Bc * 784;
    const int b0 = ch * Bc;

    // LC1 (MFMA, fused im2col): x -> h1[2704,Bc] bf16
    k_lc1m<<<dim3(Bc / 128, 13), 256, 0, stream>>>(xc, Wm1, b1, H1, Bc);
    // LC2: h1 -> h2[1152,Bc] bf16
    k_lcm<32, 144, 36, 169, 13, 6, 2, true>
        <<<dim3(Bc / 128, 36), 256, 0, stream>>>(H1, Wm2, b2, H2, Bc);
    // LC3: h2 -> h3[1024,Bc] bf16
    k_lcm<64, 288, 16, 36, 6, 4, 1, false>
        <<<dim3(Bc / 128, 16), 256, 0, stream>>>(H2, Wm3, b3, H3, Bc);
    // FC1: h3 -> h4[512,Bc] bf16
    k_fc1m<<<dim3(Bc / 128, 4), 256, 0, stream>>>(H3, Wbf, fb1, H4, Bc);
    // FC2: h4 -> out[b,10] f32
    k_fc2<<<dim3(Bc / 64), dim3(64, 4), 0, stream>>>(H4, fw2, fb2, out, Bc,
                                                     b0);
  }
}